// Round 1
// 1048.809 us; speedup vs baseline: 1.0754x; 1.0754x over previous
//
#include <hip/hip_runtime.h>
#include <hip/hip_bf16.h>
#include <hip/hip_fp16.h>

// GAT fused pipeline for MI355X.
// R11: k_msg is miss-path bound (R6-R10 plateau 390-460 GB/s, FETCH 144B/edge,
// VALU 10%). Only lever = fewer cache lines per edge. h payload -> fp8 e4m3
// (HW v_cvt_pk_fp8_f32), row 256B->128B, working set 25.6->12.8MB.
// a_src/a_dst now computed in k_gemm epilogue from fp32 accumulators
// (better precision than old fp16-h dot; k_attn deleted; h16 deleted;
// ws 36.9 -> ~24MB). Decisive risk: absmax 1.2e-4 -> predicted 3-6e-4.

#define N_NODES 100000
#define N_EDGE  1600000
#define N_ET    1700000   // edges + self-loops
#define N_G     100
#define HEADS   8
#define OUTC    16
#define EPS     1e-5f
#define NEG     0.2f
#define NCHUNK  3125      // 3125 * 32 == 100000

typedef unsigned int uint;
typedef unsigned short ushort;
typedef float f32x2 __attribute__((ext_vector_type(2)));

__device__ __forceinline__ float bf2f_lo(uint u){ union{uint i; float f;} c; c.i = u << 16; return c.f; }
__device__ __forceinline__ float bf2f_hi(uint u){ union{uint i; float f;} c; c.i = u & 0xffff0000u; return c.f; }
__device__ __forceinline__ float bf2f(ushort u){ union{uint i; float f;} c; c.i = ((uint)u) << 16; return c.f; }
__device__ __forceinline__ float scrub(float v){ return (v == v) ? v : 0.f; }

__device__ __forceinline__ float ldf(const void* p, int i, int f32){
  return f32 ? ((const float*)p)[i] : bf2f(((const ushort*)p)[i]);
}
__device__ __forceinline__ int ldid(const int* p, int flat, int is64){
  return is64 ? p[2 * flat] : p[flat];
}

// ---------------- dtype detection ----------------
__global__ void k_detect(const uint* __restrict__ x32, const int* __restrict__ ei32,
                         const int* __restrict__ b32, int* __restrict__ flags){
  __shared__ int cnt[3];
  int t = threadIdx.x;
  if (t < 3) cnt[t] = 0;
  __syncthreads();
  { uint w = x32[t]; uint el = (w >> 7) & 0xffu;
    if (el != 0 && (el < 110 || el > 140)) atomicAdd(&cnt[0], 1); }
  if (t < 128){ if (ei32[2 * t + 1] != 0) atomicAdd(&cnt[1], 1); }
  if (t < 128){ if (b32[98001 + 2 * t] != 0) atomicAdd(&cnt[2], 1); }
  __syncthreads();
  if (t == 0){
    flags[0] = cnt[0] > 64;  // 1 = floats are fp32
    flags[1] = cnt[1] < 32;  // 1 = edge_index is int64
    flags[2] = cnt[2] < 32;  // 1 = batch is int64
    flags[3] = 0;
  }
}

// ---------------- BN statistics: column sum / sumsq ----------------
__global__ __launch_bounds__(256) void k_bn_stats(const void* __restrict__ xraw,
                                                  const int* __restrict__ flags,
                                                  float* __restrict__ stats){
  int f32 = flags[0];
  int t = threadIdx.x;
  int c = t & 63;
  int c0 = c * 2;
  float s0 = 0.f, s1 = 0.f, q0 = 0.f, q1 = 0.f;
  if (f32){
    const float2* x2 = (const float2*)xraw;
    for (int r = blockIdx.x * 4 + (t >> 6); r < N_NODES; r += gridDim.x * 4){
      float2 v = x2[r * 64 + c];
      float f0 = scrub(v.x), f1 = scrub(v.y);
      s0 += f0; q0 += f0 * f0;
      s1 += f1; q1 += f1 * f1;
    }
  } else {
    const uint* x2 = (const uint*)xraw;
    for (int r = blockIdx.x * 4 + (t >> 6); r < N_NODES; r += gridDim.x * 4){
      uint v = x2[r * 64 + c];
      float f0 = scrub(bf2f_lo(v)), f1 = scrub(bf2f_hi(v));
      s0 += f0; q0 += f0 * f0;
      s1 += f1; q1 += f1 * f1;
    }
  }
  __shared__ float red[4][256];
  red[0][t] = s0; red[1][t] = q0; red[2][t] = s1; red[3][t] = q1;
  __syncthreads();
  if (t < 64){
    s0 = red[0][t] + red[0][t+64] + red[0][t+128] + red[0][t+192];
    q0 = red[1][t] + red[1][t+64] + red[1][t+128] + red[1][t+192];
    s1 = red[2][t] + red[2][t+64] + red[2][t+128] + red[2][t+192];
    q1 = red[3][t] + red[3][t+64] + red[3][t+128] + red[3][t+192];
    atomicAdd(&stats[c0],       s0);
    atomicAdd(&stats[c0+1],     s1);
    atomicAdd(&stats[128+c0],   q0);
    atomicAdd(&stats[128+c0+1], q1);
  }
}

// ------------- fold BN into GEMM: Wp = scale*W, bp = shift @ W ---------------
__global__ __launch_bounds__(128) void k_prep(const float* __restrict__ stats,
                                              const void* __restrict__ gamma,
                                              const void* __restrict__ beta,
                                              const void* __restrict__ W,
                                              const int* __restrict__ flags,
                                              float* __restrict__ Wp, float* __restrict__ bp){
  int f32 = flags[0];
  __shared__ float scl[128], shf[128];
  int t = threadIdx.x;
  float mean = scrub(stats[t] * (1.0f / N_NODES));
  float var  = stats[128 + t] * (1.0f / N_NODES) - mean * mean;
  if (!(var > 0.f)) var = 0.f;
  float sc = scrub(ldf(gamma, t, f32)) * rsqrtf(var + EPS);
  sc = scrub(sc);
  scl[t] = sc;
  shf[t] = scrub(scrub(ldf(beta, t, f32)) - mean * sc);
  __syncthreads();
  float b = 0.f;
  for (int c = 0; c < 128; c++){
    float w = scrub(ldf(W, c * 128 + t, f32));
    Wp[c * 128 + t] = scl[c] * w;
    b += shf[c] * w;
  }
  bp[t] = scrub(b);
}

// -------- GEMM h = x @ Wp + bp -> fp8 h8 [N][128B] + fused attn scalars ------
// Epilogue: pack fp8 e4m3 rows (HW cvt), and reduce a_src/a_dst per (row,head)
// from fp32 accumulators across the 4 lanes owning each head's 16 columns.
__global__ __launch_bounds__(256) void k_gemm(const void* __restrict__ xraw,
                                              const float* __restrict__ Wp,
                                              const float* __restrict__ bp,
                                              const void* __restrict__ att_src,
                                              const void* __restrict__ att_dst,
                                              const int* __restrict__ flags,
                                              unsigned char* __restrict__ h8,
                                              __half* __restrict__ a_src16,
                                              __half* __restrict__ a_dst16){
  int f32 = flags[0];
  __shared__ float As[8][132];
  __shared__ float Bs[8][132];
  __shared__ float sS[128], sD[128];
  int t = threadIdx.x;
  int tx = t & 15, ty = t >> 4;
  if (t < 128){ sS[t] = scrub(ldf(att_src, t, f32)); sD[t] = scrub(ldf(att_dst, t, f32)); }
  int row0 = blockIdx.x * 128;
  float acc[8][8];
#pragma unroll
  for (int i = 0; i < 8; i++)
#pragma unroll
    for (int u = 0; u < 8; u++) acc[i][u] = 0.f;

  int ar = t >> 1, ak = (t & 1) * 4;
  int bk = t >> 5, bj = (t & 31) * 4;
  for (int k0 = 0; k0 < 128; k0 += 8){
    int grow = row0 + ar;
    float a0v = 0.f, a1v = 0.f, a2v = 0.f, a3v = 0.f;
    if (grow < N_NODES){
      if (f32){
        float4 r4 = *(const float4*)((const float*)xraw + (size_t)grow * 128 + k0 + ak);
        a0v = scrub(r4.x); a1v = scrub(r4.y); a2v = scrub(r4.z); a3v = scrub(r4.w);
      } else {
        uint2 raw = *(const uint2*)((const ushort*)xraw + (size_t)grow * 128 + k0 + ak);
        a0v = scrub(bf2f_lo(raw.x)); a1v = scrub(bf2f_hi(raw.x));
        a2v = scrub(bf2f_lo(raw.y)); a3v = scrub(bf2f_hi(raw.y));
      }
    }
    As[ak+0][ar] = a0v; As[ak+1][ar] = a1v; As[ak+2][ar] = a2v; As[ak+3][ar] = a3v;
    float4 wb = *(const float4*)(Wp + (k0 + bk) * 128 + bj);
    *(float4*)&Bs[bk][bj] = wb;
    __syncthreads();
#pragma unroll
    for (int k = 0; k < 8; k++){
      float4 a0 = *(const float4*)&As[k][ty * 8];
      float4 a1 = *(const float4*)&As[k][ty * 8 + 4];
      float4 b0 = *(const float4*)&Bs[k][tx * 4];
      float4 b1 = *(const float4*)&Bs[k][64 + tx * 4];
      float a[8] = {a0.x,a0.y,a0.z,a0.w,a1.x,a1.y,a1.z,a1.w};
      float b[8] = {b0.x,b0.y,b0.z,b0.w,b1.x,b1.y,b1.z,b1.w};
#pragma unroll
      for (int i = 0; i < 8; i++)
#pragma unroll
        for (int u = 0; u < 8; u++) acc[i][u] += a[i] * b[u];
    }
    __syncthreads();
  }
  float4 bl = *(const float4*)(bp + tx * 4);
  float4 bh = *(const float4*)(bp + 64 + tx * 4);
  float bb[8] = {bl.x,bl.y,bl.z,bl.w,bh.x,bh.y,bh.z,bh.w};
#pragma unroll
  for (int i = 0; i < 8; i++){
    int r = row0 + ty * 8 + i;        // uniform across tx -> shuffle groups safe
    if (r >= N_NODES) break;
    float o[8];
#pragma unroll
    for (int u = 0; u < 8; u++){
      float v = scrub(acc[i][u] + bb[u]);
      o[u] = fminf(fmaxf(v, -448.f), 448.f);   // e4m3 sat guard (values << 448)
    }
    // fp8 pack: bytes [o0,o1,o2,o3] then [o4..o7]
    uint w0 = __builtin_amdgcn_cvt_pk_fp8_f32(o[0], o[1], 0, false);
    w0 = __builtin_amdgcn_cvt_pk_fp8_f32(o[2], o[3], (int)w0, true);
    uint w1 = __builtin_amdgcn_cvt_pk_fp8_f32(o[4], o[5], 0, false);
    w1 = __builtin_amdgcn_cvt_pk_fp8_f32(o[6], o[7], (int)w1, true);
    unsigned char* po = h8 + (size_t)r * 128;
    *(uint*)(po + tx * 4)      = w0;
    *(uint*)(po + 64 + tx * 4) = w1;
    // attention scalars from fp32 accumulators.
    // cols tx*4..+3 belong to head hA=tx>>2; cols 64+tx*4..+3 to head 4+hA.
    float pa = 0.f, pb = 0.f, qa = 0.f, qb = 0.f;
#pragma unroll
    for (int u = 0; u < 4; u++){
      pa += o[u]     * sS[tx * 4 + u];
      qa += o[u]     * sD[tx * 4 + u];
      pb += o[u + 4] * sS[64 + tx * 4 + u];
      qb += o[u + 4] * sD[64 + tx * 4 + u];
    }
    pa += __shfl_xor(pa, 1); pa += __shfl_xor(pa, 2);
    pb += __shfl_xor(pb, 1); pb += __shfl_xor(pb, 2);
    qa += __shfl_xor(qa, 1); qa += __shfl_xor(qa, 2);
    qb += __shfl_xor(qb, 1); qb += __shfl_xor(qb, 2);
    if ((tx & 3) == 0){
      int hA = tx >> 2;
      a_src16[(size_t)r * 8 + hA]     = __float2half_rn(scrub(pa));
      a_src16[(size_t)r * 8 + 4 + hA] = __float2half_rn(scrub(pb));
      a_dst16[(size_t)r * 8 + hA]     = __float2half_rn(scrub(qa));
      a_dst16[(size_t)r * 8 + 4 + hA] = __float2half_rn(scrub(qb));
    }
  }
}

// ------------------------------ CSR build ------------------------------------
__global__ void k_deg(const int* __restrict__ ei, const int* __restrict__ flags,
                      int* __restrict__ deg){
  int is64 = flags[1];
  for (int e = blockIdx.x * blockDim.x + threadIdx.x; e < N_ET; e += gridDim.x * blockDim.x){
    int d = (e < N_EDGE) ? ldid(ei, N_EDGE + e, is64) : (e - N_EDGE);
    if ((uint)d < N_NODES) atomicAdd(&deg[d], 1);
  }
}

__global__ void k_scan1(const int* __restrict__ deg, int* __restrict__ chunk){
  int i = blockIdx.x * blockDim.x + threadIdx.x;
  if (i >= NCHUNK) return;
  const int4* dp = (const int4*)(deg + i * 32);
  int s = 0;
#pragma unroll
  for (int j = 0; j < 8; j++){ int4 v = dp[j]; s += v.x + v.y + v.z + v.w; }
  chunk[i] = s;
}

__global__ __launch_bounds__(1024) void k_scan2(int* __restrict__ chunk){
  __shared__ int sdat[1024];
  int t = threadIdx.x;
  int v[4]; int tot = 0;
#pragma unroll
  for (int j = 0; j < 4; j++){
    int c = t * 4 + j;
    v[j] = (c < NCHUNK) ? chunk[c] : 0;
    tot += v[j];
  }
  sdat[t] = tot;
  __syncthreads();
  for (int off = 1; off < 1024; off <<= 1){
    int add = (t >= off) ? sdat[t - off] : 0;
    __syncthreads();
    sdat[t] += add;
    __syncthreads();
  }
  int run = sdat[t] - tot;   // exclusive
#pragma unroll
  for (int j = 0; j < 4; j++){
    int c = t * 4 + j;
    if (c < NCHUNK) chunk[c] = run;
    run += v[j];
  }
}

__global__ void k_scan3(const int* __restrict__ deg, const int* __restrict__ chunk, int* __restrict__ offsets){
  int i = blockIdx.x * blockDim.x + threadIdx.x;
  if (i >= NCHUNK) return;
  int run = chunk[i];
  for (int j = 0; j < 32; j++){
    int idx = i * 32 + j;
    offsets[idx] = run;
    run += deg[idx];
  }
  if (i == NCHUNK - 1) offsets[N_NODES] = run;
}

__global__ void k_scatter(const int* __restrict__ ei, const int* __restrict__ flags,
                          const int* __restrict__ offsets, int* __restrict__ cursor, int* __restrict__ csr){
  int is64 = flags[1];
  for (int e = blockIdx.x * blockDim.x + threadIdx.x; e < N_ET; e += gridDim.x * blockDim.x){
    int s, d;
    if (e < N_EDGE){ s = ldid(ei, e, is64); d = ldid(ei, N_EDGE + e, is64); }
    else { s = e - N_EDGE; d = s; }
    if ((uint)d >= N_NODES) continue;
    int pos = atomicAdd(&cursor[d], 1);
    int slot = offsets[d] + pos;
    if ((uint)slot < N_ET) csr[slot] = s;
  }
}

// ------ fused: inline softmax + fp8 gather + head-mean + ELU + pool.
// One wave per node, lane owns channels 2*lane,2*lane+1 (head myh=lane>>3).
// 8-edge batch, 16 NAMED scalar loads -> sched_barrier(0) -> cvt+math.
// h row now 128B fp8 (2 cache lines/edge instead of 4).
__global__ __launch_bounds__(256) void k_msg(const int* __restrict__ offsets, const int* __restrict__ csr,
                                             const __half* __restrict__ a_src16, const __half* __restrict__ a_dst16,
                                             const ushort* __restrict__ h8, const void* __restrict__ bias,
                                             const int* __restrict__ batch, const int* __restrict__ flags,
                                             float* __restrict__ pool, float* __restrict__ cntg){
  int f32 = flags[0], b64 = flags[2];
  int t = threadIdx.x;
  int wv = t >> 6, lane = t & 63;
  int n = blockIdx.x * 4 + wv;        // grid = N/4 exactly
  int myh = lane >> 3;
  int start = offsets[n], end = offsets[n + 1];
  float ad = __half2float(a_dst16[(size_t)n * 8 + myh]);
  const ushort* as16 = (const ushort*)a_src16;
  float acc0 = 0.f, acc1 = 0.f, den = 0.f;

  for (int base = start; base < end; base += 64){
    int cnt = min(64, end - base);
    int sreg = csr[min(base + lane, N_ET - 1)];
    int jj = 0;
    for (; jj + 8 <= cnt; jj += 8){
      int s0 = __shfl(sreg, jj);
      int s1 = __shfl(sreg, jj + 1);
      int s2 = __shfl(sreg, jj + 2);
      int s3 = __shfl(sreg, jj + 3);
      int s4 = __shfl(sreg, jj + 4);
      int s5 = __shfl(sreg, jj + 5);
      int s6 = __shfl(sreg, jj + 6);
      int s7 = __shfl(sreg, jj + 7);
      ushort h0 = h8[(size_t)s0 * 64 + lane];
      ushort h1 = h8[(size_t)s1 * 64 + lane];
      ushort h2 = h8[(size_t)s2 * 64 + lane];
      ushort h3 = h8[(size_t)s3 * 64 + lane];
      ushort h4 = h8[(size_t)s4 * 64 + lane];
      ushort h5 = h8[(size_t)s5 * 64 + lane];
      ushort h6 = h8[(size_t)s6 * 64 + lane];
      ushort h7 = h8[(size_t)s7 * 64 + lane];
      ushort a0 = as16[(size_t)s0 * 8 + myh];
      ushort a1 = as16[(size_t)s1 * 8 + myh];
      ushort a2 = as16[(size_t)s2 * 8 + myh];
      ushort a3 = as16[(size_t)s3 * 8 + myh];
      ushort a4 = as16[(size_t)s4 * 8 + myh];
      ushort a5 = as16[(size_t)s5 * 8 + myh];
      ushort a6 = as16[(size_t)s6 * 8 + myh];
      ushort a7 = as16[(size_t)s7 * 8 + myh];
      __builtin_amdgcn_sched_barrier(0);   // all 16 loads issue before math
#define EDGE(AA, HH)                                              \
      { float e = __half2float(*(__half*)&(AA)) + ad;             \
        e = e > 0.f ? e : NEG * e;                                \
        float p = __expf(fminf(e, 30.f));                         \
        f32x2 hv = __builtin_amdgcn_cvt_pk_f32_fp8((int)(HH), false); \
        den += p; acc0 += p * hv[0]; acc1 += p * hv[1]; }
      EDGE(a0, h0) EDGE(a1, h1) EDGE(a2, h2) EDGE(a3, h3)
      EDGE(a4, h4) EDGE(a5, h5) EDGE(a6, h6) EDGE(a7, h7)
#undef EDGE
    }
    for (; jj < cnt; jj++){
      int s0 = __shfl(sreg, jj);
      ushort hh = h8[(size_t)s0 * 64 + lane];
      ushort a0 = as16[(size_t)s0 * 8 + myh];
      float e = __half2float(*(__half*)&a0) + ad;
      e = e > 0.f ? e : NEG * e;
      float p = __expf(fminf(e, 30.f));
      f32x2 hv = __builtin_amdgcn_cvt_pk_f32_fp8((int)hh, false);
      den += p; acc0 += p * hv[0]; acc1 += p * hv[1];
    }
  }

  float inv = (den > 0.f) ? (1.0f / den) : 0.f;   // den>0 via self-loop
  float v0 = acc0 * inv, v1 = acc1 * inv;
  // head mean: sum over lane bits 3,4,5 (heads)
  v0 += __shfl_xor(v0, 8);  v1 += __shfl_xor(v1, 8);
  v0 += __shfl_xor(v0, 16); v1 += __shfl_xor(v1, 16);
  v0 += __shfl_xor(v0, 32); v1 += __shfl_xor(v1, 32);
  if (lane < 8){
    int c0 = lane * 2;
    float o0 = v0 * 0.125f + scrub(ldf(bias, c0, f32));
    float o1 = v1 * 0.125f + scrub(ldf(bias, c0 + 1, f32));
    o0 = o0 > 0.f ? o0 : (__expf(o0) - 1.0f);
    o1 = o1 > 0.f ? o1 : (__expf(o1) - 1.0f);
    int g = ldid(batch, n, b64);
    if ((uint)g < N_G){
      atomicAdd(&pool[g * 16 + c0],     scrub(o0));
      atomicAdd(&pool[g * 16 + c0 + 1], scrub(o1));
      if (lane == 0) atomicAdd(&cntg[g], 1.0f);
    }
  }
}

// ---- final: divide by counts, write FP32 (reference output dtype) ----
__global__ void k_final(const float* __restrict__ pool, const float* __restrict__ cntg,
                        float* __restrict__ out){
  int i = blockIdx.x * blockDim.x + threadIdx.x;
  if (i >= N_G * OUTC) return;
  int g = i >> 4;
  out[i] = scrub(pool[i] / fmaxf(cntg[g], 1.0f));
}

// -----------------------------------------------------------------------------
extern "C" void kernel_launch(void* const* d_in, const int* in_sizes, int n_in,
                              void* d_out, int out_size, void* d_ws, size_t ws_size,
                              hipStream_t stream){
  (void)in_sizes; (void)n_in; (void)out_size; (void)ws_size;
  const void* x     = d_in[0];
  const int*  ei    = (const int*)d_in[1];
  const int*  batch = (const int*)d_in[2];
  const void* gamma = d_in[3];
  const void* beta  = d_in[4];
  const void* W     = d_in[5];
  const void* att_s = d_in[6];
  const void* att_d = d_in[7];
  const void* bias  = d_in[8];

  // ws total ~24.1 MB (h16 removed; h8 fp8 12.8MB added; csr last).
  char* ws = (char*)d_ws;
  size_t off = 0;
  auto alloc = [&](size_t b){ size_t r = off; off += (b + 255) & ~(size_t)255; return r; };
  int*    flags   = (int*)(ws + alloc(4 * 4));
  float*  stats   = (float*)(ws + alloc(256 * 4));
  float*  Wp      = (float*)(ws + alloc(16384 * 4));
  float*  bp      = (float*)(ws + alloc(128 * 4));
  float*  pool    = (float*)(ws + alloc(N_G * 16 * 4));
  float*  cntg    = (float*)(ws + alloc(N_G * 4));
  int*    chunk   = (int*)(ws + alloc(4096 * 4));
  int*    offsets = (int*)(ws + alloc((size_t)(N_NODES + 1) * 4));
  int*    deg     = (int*)(ws + alloc((size_t)N_NODES * 4));
  int*    cursor  = (int*)(ws + alloc((size_t)N_NODES * 4));
  __half* a_src16 = (__half*)(ws + alloc((size_t)N_NODES * 8 * 2));
  __half* a_dst16 = (__half*)(ws + alloc((size_t)N_NODES * 8 * 2));
  unsigned char* h8 = (unsigned char*)(ws + alloc((size_t)N_NODES * 128));
  int*    csr     = (int*)(ws + alloc((size_t)N_ET * 4));

  hipMemsetAsync(stats,  0, 256 * 4, stream);
  hipMemsetAsync(deg,    0, (size_t)N_NODES * 4, stream);
  hipMemsetAsync(cursor, 0, (size_t)N_NODES * 4, stream);
  hipMemsetAsync(pool,   0, N_G * 16 * 4, stream);
  hipMemsetAsync(cntg,   0, N_G * 4, stream);

  k_detect<<<1, 256, 0, stream>>>((const uint*)x, ei, batch, flags);
  k_bn_stats<<<512, 256, 0, stream>>>(x, flags, stats);
  k_prep<<<1, 128, 0, stream>>>(stats, gamma, beta, W, flags, Wp, bp);
  k_gemm<<<(N_NODES + 127) / 128, 256, 0, stream>>>(x, Wp, bp, att_s, att_d, flags, h8, a_src16, a_dst16);
  k_deg<<<1024, 256, 0, stream>>>(ei, flags, deg);
  k_scan1<<<(NCHUNK + 255) / 256, 256, 0, stream>>>(deg, chunk);
  k_scan2<<<1, 1024, 0, stream>>>(chunk);
  k_scan3<<<(NCHUNK + 255) / 256, 256, 0, stream>>>(deg, chunk, offsets);
  k_scatter<<<1024, 256, 0, stream>>>(ei, flags, offsets, cursor, csr);
  k_msg<<<N_NODES / 4, 256, 0, stream>>>(offsets, csr, a_src16, a_dst16, (const ushort*)h8, bias, batch, flags, pool, cntg);
  k_final<<<(N_G * OUTC + 255) / 256, 256, 0, stream>>>(pool, cntg, (float*)d_out);
}

// Round 2
// 529.934 us; speedup vs baseline: 2.1283x; 1.9791x over previous
//
#include <hip/hip_runtime.h>
#include <hip/hip_bf16.h>
#include <hip/hip_fp16.h>

// GAT fused pipeline for MI355X.
// R12: HYPOTHESIS = k_msg's 650-760us plateau (invariant to payload bytes
// across R6-R11; VALU 9%, BW 182-460 GB/s, occ 72%) is GLOBAL ATOMIC
// SERIALIZATION: 1.6M fp32 atomics to 1600 addrs (~50 lines), batch-sorted
// so all CUs hit the same 1-2 lines simultaneously -> one TCC channel
// serializes + backpressures the vmem pipes. Fix: k_msg stores per-node
// post-ELU vectors to dense out_n[N][16] (plain stores, NO atomics);
// new k_pool (1 block/graph, binary search sorted batch, segmented reduce)
// writes d_out directly. k_final/pool/cntg deleted.
// Prediction: k_msg 760 -> 100-250us if theory right; unchanged if wrong.

#define N_NODES 100000
#define N_EDGE  1600000
#define N_ET    1700000   // edges + self-loops
#define N_G     100
#define HEADS   8
#define OUTC    16
#define EPS     1e-5f
#define NEG     0.2f
#define NCHUNK  3125      // 3125 * 32 == 100000

typedef unsigned int uint;
typedef unsigned short ushort;
typedef float f32x2 __attribute__((ext_vector_type(2)));

__device__ __forceinline__ float bf2f_lo(uint u){ union{uint i; float f;} c; c.i = u << 16; return c.f; }
__device__ __forceinline__ float bf2f_hi(uint u){ union{uint i; float f;} c; c.i = u & 0xffff0000u; return c.f; }
__device__ __forceinline__ float bf2f(ushort u){ union{uint i; float f;} c; c.i = ((uint)u) << 16; return c.f; }
__device__ __forceinline__ float scrub(float v){ return (v == v) ? v : 0.f; }

__device__ __forceinline__ float ldf(const void* p, int i, int f32){
  return f32 ? ((const float*)p)[i] : bf2f(((const ushort*)p)[i]);
}
__device__ __forceinline__ int ldid(const int* p, int flat, int is64){
  return is64 ? p[2 * flat] : p[flat];
}

// ---------------- dtype detection ----------------
__global__ void k_detect(const uint* __restrict__ x32, const int* __restrict__ ei32,
                         const int* __restrict__ b32, int* __restrict__ flags){
  __shared__ int cnt[3];
  int t = threadIdx.x;
  if (t < 3) cnt[t] = 0;
  __syncthreads();
  { uint w = x32[t]; uint el = (w >> 7) & 0xffu;
    if (el != 0 && (el < 110 || el > 140)) atomicAdd(&cnt[0], 1); }
  if (t < 128){ if (ei32[2 * t + 1] != 0) atomicAdd(&cnt[1], 1); }
  if (t < 128){ if (b32[98001 + 2 * t] != 0) atomicAdd(&cnt[2], 1); }
  __syncthreads();
  if (t == 0){
    flags[0] = cnt[0] > 64;  // 1 = floats are fp32
    flags[1] = cnt[1] < 32;  // 1 = edge_index is int64
    flags[2] = cnt[2] < 32;  // 1 = batch is int64
    flags[3] = 0;
  }
}

// ---------------- BN statistics: column sum / sumsq ----------------
__global__ __launch_bounds__(256) void k_bn_stats(const void* __restrict__ xraw,
                                                  const int* __restrict__ flags,
                                                  float* __restrict__ stats){
  int f32 = flags[0];
  int t = threadIdx.x;
  int c = t & 63;
  int c0 = c * 2;
  float s0 = 0.f, s1 = 0.f, q0 = 0.f, q1 = 0.f;
  if (f32){
    const float2* x2 = (const float2*)xraw;
    for (int r = blockIdx.x * 4 + (t >> 6); r < N_NODES; r += gridDim.x * 4){
      float2 v = x2[r * 64 + c];
      float f0 = scrub(v.x), f1 = scrub(v.y);
      s0 += f0; q0 += f0 * f0;
      s1 += f1; q1 += f1 * f1;
    }
  } else {
    const uint* x2 = (const uint*)xraw;
    for (int r = blockIdx.x * 4 + (t >> 6); r < N_NODES; r += gridDim.x * 4){
      uint v = x2[r * 64 + c];
      float f0 = scrub(bf2f_lo(v)), f1 = scrub(bf2f_hi(v));
      s0 += f0; q0 += f0 * f0;
      s1 += f1; q1 += f1 * f1;
    }
  }
  __shared__ float red[4][256];
  red[0][t] = s0; red[1][t] = q0; red[2][t] = s1; red[3][t] = q1;
  __syncthreads();
  if (t < 64){
    s0 = red[0][t] + red[0][t+64] + red[0][t+128] + red[0][t+192];
    q0 = red[1][t] + red[1][t+64] + red[1][t+128] + red[1][t+192];
    s1 = red[2][t] + red[2][t+64] + red[2][t+128] + red[2][t+192];
    q1 = red[3][t] + red[3][t+64] + red[3][t+128] + red[3][t+192];
    atomicAdd(&stats[c0],       s0);
    atomicAdd(&stats[c0+1],     s1);
    atomicAdd(&stats[128+c0],   q0);
    atomicAdd(&stats[128+c0+1], q1);
  }
}

// ------------- fold BN into GEMM: Wp = scale*W, bp = shift @ W ---------------
__global__ __launch_bounds__(128) void k_prep(const float* __restrict__ stats,
                                              const void* __restrict__ gamma,
                                              const void* __restrict__ beta,
                                              const void* __restrict__ W,
                                              const int* __restrict__ flags,
                                              float* __restrict__ Wp, float* __restrict__ bp){
  int f32 = flags[0];
  __shared__ float scl[128], shf[128];
  int t = threadIdx.x;
  float mean = scrub(stats[t] * (1.0f / N_NODES));
  float var  = stats[128 + t] * (1.0f / N_NODES) - mean * mean;
  if (!(var > 0.f)) var = 0.f;
  float sc = scrub(ldf(gamma, t, f32)) * rsqrtf(var + EPS);
  sc = scrub(sc);
  scl[t] = sc;
  shf[t] = scrub(scrub(ldf(beta, t, f32)) - mean * sc);
  __syncthreads();
  float b = 0.f;
  for (int c = 0; c < 128; c++){
    float w = scrub(ldf(W, c * 128 + t, f32));
    Wp[c * 128 + t] = scl[c] * w;
    b += shf[c] * w;
  }
  bp[t] = scrub(b);
}

// -------- GEMM h = x @ Wp + bp -> fp8 h8 [N][128B] + fused attn scalars ------
// Epilogue: pack fp8 e4m3 rows (HW cvt), and reduce a_src/a_dst per (row,head)
// from fp32 accumulators across the 4 lanes owning each head's 16 columns.
__global__ __launch_bounds__(256) void k_gemm(const void* __restrict__ xraw,
                                              const float* __restrict__ Wp,
                                              const float* __restrict__ bp,
                                              const void* __restrict__ att_src,
                                              const void* __restrict__ att_dst,
                                              const int* __restrict__ flags,
                                              unsigned char* __restrict__ h8,
                                              __half* __restrict__ a_src16,
                                              __half* __restrict__ a_dst16){
  int f32 = flags[0];
  __shared__ float As[8][132];
  __shared__ float Bs[8][132];
  __shared__ float sS[128], sD[128];
  int t = threadIdx.x;
  int tx = t & 15, ty = t >> 4;
  if (t < 128){ sS[t] = scrub(ldf(att_src, t, f32)); sD[t] = scrub(ldf(att_dst, t, f32)); }
  int row0 = blockIdx.x * 128;
  float acc[8][8];
#pragma unroll
  for (int i = 0; i < 8; i++)
#pragma unroll
    for (int u = 0; u < 8; u++) acc[i][u] = 0.f;

  int ar = t >> 1, ak = (t & 1) * 4;
  int bk = t >> 5, bj = (t & 31) * 4;
  for (int k0 = 0; k0 < 128; k0 += 8){
    int grow = row0 + ar;
    float a0v = 0.f, a1v = 0.f, a2v = 0.f, a3v = 0.f;
    if (grow < N_NODES){
      if (f32){
        float4 r4 = *(const float4*)((const float*)xraw + (size_t)grow * 128 + k0 + ak);
        a0v = scrub(r4.x); a1v = scrub(r4.y); a2v = scrub(r4.z); a3v = scrub(r4.w);
      } else {
        uint2 raw = *(const uint2*)((const ushort*)xraw + (size_t)grow * 128 + k0 + ak);
        a0v = scrub(bf2f_lo(raw.x)); a1v = scrub(bf2f_hi(raw.x));
        a2v = scrub(bf2f_lo(raw.y)); a3v = scrub(bf2f_hi(raw.y));
      }
    }
    As[ak+0][ar] = a0v; As[ak+1][ar] = a1v; As[ak+2][ar] = a2v; As[ak+3][ar] = a3v;
    float4 wb = *(const float4*)(Wp + (k0 + bk) * 128 + bj);
    *(float4*)&Bs[bk][bj] = wb;
    __syncthreads();
#pragma unroll
    for (int k = 0; k < 8; k++){
      float4 a0 = *(const float4*)&As[k][ty * 8];
      float4 a1 = *(const float4*)&As[k][ty * 8 + 4];
      float4 b0 = *(const float4*)&Bs[k][tx * 4];
      float4 b1 = *(const float4*)&Bs[k][64 + tx * 4];
      float a[8] = {a0.x,a0.y,a0.z,a0.w,a1.x,a1.y,a1.z,a1.w};
      float b[8] = {b0.x,b0.y,b0.z,b0.w,b1.x,b1.y,b1.z,b1.w};
#pragma unroll
      for (int i = 0; i < 8; i++)
#pragma unroll
        for (int u = 0; u < 8; u++) acc[i][u] += a[i] * b[u];
    }
    __syncthreads();
  }
  float4 bl = *(const float4*)(bp + tx * 4);
  float4 bh = *(const float4*)(bp + 64 + tx * 4);
  float bb[8] = {bl.x,bl.y,bl.z,bl.w,bh.x,bh.y,bh.z,bh.w};
#pragma unroll
  for (int i = 0; i < 8; i++){
    int r = row0 + ty * 8 + i;        // uniform across tx -> shuffle groups safe
    if (r >= N_NODES) break;
    float o[8];
#pragma unroll
    for (int u = 0; u < 8; u++){
      float v = scrub(acc[i][u] + bb[u]);
      o[u] = fminf(fmaxf(v, -448.f), 448.f);   // e4m3 sat guard (values << 448)
    }
    // fp8 pack: bytes [o0,o1,o2,o3] then [o4..o7]
    uint w0 = __builtin_amdgcn_cvt_pk_fp8_f32(o[0], o[1], 0, false);
    w0 = __builtin_amdgcn_cvt_pk_fp8_f32(o[2], o[3], (int)w0, true);
    uint w1 = __builtin_amdgcn_cvt_pk_fp8_f32(o[4], o[5], 0, false);
    w1 = __builtin_amdgcn_cvt_pk_fp8_f32(o[6], o[7], (int)w1, true);
    unsigned char* po = h8 + (size_t)r * 128;
    *(uint*)(po + tx * 4)      = w0;
    *(uint*)(po + 64 + tx * 4) = w1;
    // attention scalars from fp32 accumulators.
    // cols tx*4..+3 belong to head hA=tx>>2; cols 64+tx*4..+3 to head 4+hA.
    float pa = 0.f, pb = 0.f, qa = 0.f, qb = 0.f;
#pragma unroll
    for (int u = 0; u < 4; u++){
      pa += o[u]     * sS[tx * 4 + u];
      qa += o[u]     * sD[tx * 4 + u];
      pb += o[u + 4] * sS[64 + tx * 4 + u];
      qb += o[u + 4] * sD[64 + tx * 4 + u];
    }
    pa += __shfl_xor(pa, 1); pa += __shfl_xor(pa, 2);
    pb += __shfl_xor(pb, 1); pb += __shfl_xor(pb, 2);
    qa += __shfl_xor(qa, 1); qa += __shfl_xor(qa, 2);
    qb += __shfl_xor(qb, 1); qb += __shfl_xor(qb, 2);
    if ((tx & 3) == 0){
      int hA = tx >> 2;
      a_src16[(size_t)r * 8 + hA]     = __float2half_rn(scrub(pa));
      a_src16[(size_t)r * 8 + 4 + hA] = __float2half_rn(scrub(pb));
      a_dst16[(size_t)r * 8 + hA]     = __float2half_rn(scrub(qa));
      a_dst16[(size_t)r * 8 + 4 + hA] = __float2half_rn(scrub(qb));
    }
  }
}

// ------------------------------ CSR build ------------------------------------
__global__ void k_deg(const int* __restrict__ ei, const int* __restrict__ flags,
                      int* __restrict__ deg){
  int is64 = flags[1];
  for (int e = blockIdx.x * blockDim.x + threadIdx.x; e < N_ET; e += gridDim.x * blockDim.x){
    int d = (e < N_EDGE) ? ldid(ei, N_EDGE + e, is64) : (e - N_EDGE);
    if ((uint)d < N_NODES) atomicAdd(&deg[d], 1);
  }
}

__global__ void k_scan1(const int* __restrict__ deg, int* __restrict__ chunk){
  int i = blockIdx.x * blockDim.x + threadIdx.x;
  if (i >= NCHUNK) return;
  const int4* dp = (const int4*)(deg + i * 32);
  int s = 0;
#pragma unroll
  for (int j = 0; j < 8; j++){ int4 v = dp[j]; s += v.x + v.y + v.z + v.w; }
  chunk[i] = s;
}

__global__ __launch_bounds__(1024) void k_scan2(int* __restrict__ chunk){
  __shared__ int sdat[1024];
  int t = threadIdx.x;
  int v[4]; int tot = 0;
#pragma unroll
  for (int j = 0; j < 4; j++){
    int c = t * 4 + j;
    v[j] = (c < NCHUNK) ? chunk[c] : 0;
    tot += v[j];
  }
  sdat[t] = tot;
  __syncthreads();
  for (int off = 1; off < 1024; off <<= 1){
    int add = (t >= off) ? sdat[t - off] : 0;
    __syncthreads();
    sdat[t] += add;
    __syncthreads();
  }
  int run = sdat[t] - tot;   // exclusive
#pragma unroll
  for (int j = 0; j < 4; j++){
    int c = t * 4 + j;
    if (c < NCHUNK) chunk[c] = run;
    run += v[j];
  }
}

__global__ void k_scan3(const int* __restrict__ deg, const int* __restrict__ chunk, int* __restrict__ offsets){
  int i = blockIdx.x * blockDim.x + threadIdx.x;
  if (i >= NCHUNK) return;
  int run = chunk[i];
  for (int j = 0; j < 32; j++){
    int idx = i * 32 + j;
    offsets[idx] = run;
    run += deg[idx];
  }
  if (i == NCHUNK - 1) offsets[N_NODES] = run;
}

__global__ void k_scatter(const int* __restrict__ ei, const int* __restrict__ flags,
                          const int* __restrict__ offsets, int* __restrict__ cursor, int* __restrict__ csr){
  int is64 = flags[1];
  for (int e = blockIdx.x * blockDim.x + threadIdx.x; e < N_ET; e += gridDim.x * blockDim.x){
    int s, d;
    if (e < N_EDGE){ s = ldid(ei, e, is64); d = ldid(ei, N_EDGE + e, is64); }
    else { s = e - N_EDGE; d = s; }
    if ((uint)d >= N_NODES) continue;
    int pos = atomicAdd(&cursor[d], 1);
    int slot = offsets[d] + pos;
    if ((uint)slot < N_ET) csr[slot] = s;
  }
}

// ------ fused: inline softmax + fp8 gather + head-mean + ELU -> out_n.
// One wave per node, lane owns channels 2*lane,2*lane+1 (head myh=lane>>3).
// 8-edge batch, 16 NAMED scalar loads -> sched_barrier(0) -> cvt+math.
// R12: NO global atomics — plain 64B store of the node vector to out_n.
__global__ __launch_bounds__(256) void k_msg(const int* __restrict__ offsets, const int* __restrict__ csr,
                                             const __half* __restrict__ a_src16, const __half* __restrict__ a_dst16,
                                             const ushort* __restrict__ h8, const void* __restrict__ bias,
                                             const int* __restrict__ flags,
                                             float* __restrict__ out_n){
  int f32 = flags[0];
  int t = threadIdx.x;
  int wv = t >> 6, lane = t & 63;
  int n = blockIdx.x * 4 + wv;        // grid = N/4 exactly
  int myh = lane >> 3;
  int start = offsets[n], end = offsets[n + 1];
  float ad = __half2float(a_dst16[(size_t)n * 8 + myh]);
  const ushort* as16 = (const ushort*)a_src16;
  float acc0 = 0.f, acc1 = 0.f, den = 0.f;

  for (int base = start; base < end; base += 64){
    int cnt = min(64, end - base);
    int sreg = csr[min(base + lane, N_ET - 1)];
    int jj = 0;
    for (; jj + 8 <= cnt; jj += 8){
      int s0 = __shfl(sreg, jj);
      int s1 = __shfl(sreg, jj + 1);
      int s2 = __shfl(sreg, jj + 2);
      int s3 = __shfl(sreg, jj + 3);
      int s4 = __shfl(sreg, jj + 4);
      int s5 = __shfl(sreg, jj + 5);
      int s6 = __shfl(sreg, jj + 6);
      int s7 = __shfl(sreg, jj + 7);
      ushort h0 = h8[(size_t)s0 * 64 + lane];
      ushort h1 = h8[(size_t)s1 * 64 + lane];
      ushort h2 = h8[(size_t)s2 * 64 + lane];
      ushort h3 = h8[(size_t)s3 * 64 + lane];
      ushort h4 = h8[(size_t)s4 * 64 + lane];
      ushort h5 = h8[(size_t)s5 * 64 + lane];
      ushort h6 = h8[(size_t)s6 * 64 + lane];
      ushort h7 = h8[(size_t)s7 * 64 + lane];
      ushort a0 = as16[(size_t)s0 * 8 + myh];
      ushort a1 = as16[(size_t)s1 * 8 + myh];
      ushort a2 = as16[(size_t)s2 * 8 + myh];
      ushort a3 = as16[(size_t)s3 * 8 + myh];
      ushort a4 = as16[(size_t)s4 * 8 + myh];
      ushort a5 = as16[(size_t)s5 * 8 + myh];
      ushort a6 = as16[(size_t)s6 * 8 + myh];
      ushort a7 = as16[(size_t)s7 * 8 + myh];
      __builtin_amdgcn_sched_barrier(0);   // all 16 loads issue before math
#define EDGE(AA, HH)                                              \
      { float e = __half2float(*(__half*)&(AA)) + ad;             \
        e = e > 0.f ? e : NEG * e;                                \
        float p = __expf(fminf(e, 30.f));                         \
        f32x2 hv = __builtin_amdgcn_cvt_pk_f32_fp8((int)(HH), false); \
        den += p; acc0 += p * hv[0]; acc1 += p * hv[1]; }
      EDGE(a0, h0) EDGE(a1, h1) EDGE(a2, h2) EDGE(a3, h3)
      EDGE(a4, h4) EDGE(a5, h5) EDGE(a6, h6) EDGE(a7, h7)
#undef EDGE
    }
    for (; jj < cnt; jj++){
      int s0 = __shfl(sreg, jj);
      ushort hh = h8[(size_t)s0 * 64 + lane];
      ushort a0 = as16[(size_t)s0 * 8 + myh];
      float e = __half2float(*(__half*)&a0) + ad;
      e = e > 0.f ? e : NEG * e;
      float p = __expf(fminf(e, 30.f));
      f32x2 hv = __builtin_amdgcn_cvt_pk_f32_fp8((int)hh, false);
      den += p; acc0 += p * hv[0]; acc1 += p * hv[1];
    }
  }

  float inv = (den > 0.f) ? (1.0f / den) : 0.f;   // den>0 via self-loop
  float v0 = acc0 * inv, v1 = acc1 * inv;
  // head mean: sum over lane bits 3,4,5 (heads)
  v0 += __shfl_xor(v0, 8);  v1 += __shfl_xor(v1, 8);
  v0 += __shfl_xor(v0, 16); v1 += __shfl_xor(v1, 16);
  v0 += __shfl_xor(v0, 32); v1 += __shfl_xor(v1, 32);
  if (lane < 8){
    int c0 = lane * 2;
    float o0 = v0 * 0.125f + scrub(ldf(bias, c0, f32));
    float o1 = v1 * 0.125f + scrub(ldf(bias, c0 + 1, f32));
    o0 = o0 > 0.f ? o0 : (__expf(o0) - 1.0f);
    o1 = o1 > 0.f ? o1 : (__expf(o1) - 1.0f);
    float2* po = (float2*)(out_n + (size_t)n * 16);
    po[lane] = make_float2(scrub(o0), scrub(o1));   // 64B/wave, no atomics
  }
}

// ---- pool: 1 block per graph. Binary-search sorted batch for the segment,
// segmented fp32 reduce of out_n, divide by count, write d_out directly. ----
__global__ __launch_bounds__(256) void k_pool(const float* __restrict__ out_n,
                                              const int* __restrict__ batch,
                                              const int* __restrict__ flags,
                                              float* __restrict__ out){
  int b64 = flags[2];
  int g = blockIdx.x;                  // N_G blocks
  int t = threadIdx.x;
  int c = t & 15, rg = t >> 4;         // 16 channels x 16 row-groups
  // lower bound of g
  int lo = 0, hi = N_NODES;
  while (lo < hi){ int m = (lo + hi) >> 1; if (ldid(batch, m, b64) < g) lo = m + 1; else hi = m; }
  // lower bound of g+1
  int lo2 = lo, hi2 = N_NODES;
  while (lo2 < hi2){ int m = (lo2 + hi2) >> 1; if (ldid(batch, m, b64) < g + 1) lo2 = m + 1; else hi2 = m; }
  float acc = 0.f;
  for (int r = lo + rg; r < lo2; r += 16)
    acc += out_n[(size_t)r * 16 + c];
  __shared__ float red[16][17];
  red[rg][c] = acc;
  __syncthreads();
  if (t < 16){
    float v = 0.f;
#pragma unroll
    for (int i = 0; i < 16; i++) v += red[i][t];
    float cntf = (float)(lo2 - lo);
    out[g * 16 + t] = scrub(v / fmaxf(cntf, 1.0f));
  }
}

// -----------------------------------------------------------------------------
extern "C" void kernel_launch(void* const* d_in, const int* in_sizes, int n_in,
                              void* d_out, int out_size, void* d_ws, size_t ws_size,
                              hipStream_t stream){
  (void)in_sizes; (void)n_in; (void)out_size; (void)ws_size;
  const void* x     = d_in[0];
  const int*  ei    = (const int*)d_in[1];
  const int*  batch = (const int*)d_in[2];
  const void* gamma = d_in[3];
  const void* beta  = d_in[4];
  const void* W     = d_in[5];
  const void* att_s = d_in[6];
  const void* att_d = d_in[7];
  const void* bias  = d_in[8];

  // ws total ~30.6 MB (h8 12.8MB, out_n 6.4MB, csr last).
  char* ws = (char*)d_ws;
  size_t off = 0;
  auto alloc = [&](size_t b){ size_t r = off; off += (b + 255) & ~(size_t)255; return r; };
  int*    flags   = (int*)(ws + alloc(4 * 4));
  float*  stats   = (float*)(ws + alloc(256 * 4));
  float*  Wp      = (float*)(ws + alloc(16384 * 4));
  float*  bp      = (float*)(ws + alloc(128 * 4));
  int*    chunk   = (int*)(ws + alloc(4096 * 4));
  int*    offsets = (int*)(ws + alloc((size_t)(N_NODES + 1) * 4));
  int*    deg     = (int*)(ws + alloc((size_t)N_NODES * 4));
  int*    cursor  = (int*)(ws + alloc((size_t)N_NODES * 4));
  __half* a_src16 = (__half*)(ws + alloc((size_t)N_NODES * 8 * 2));
  __half* a_dst16 = (__half*)(ws + alloc((size_t)N_NODES * 8 * 2));
  float*  out_n   = (float*)(ws + alloc((size_t)N_NODES * 16 * 4));
  unsigned char* h8 = (unsigned char*)(ws + alloc((size_t)N_NODES * 128));
  int*    csr     = (int*)(ws + alloc((size_t)N_ET * 4));

  hipMemsetAsync(stats,  0, 256 * 4, stream);
  hipMemsetAsync(deg,    0, (size_t)N_NODES * 4, stream);
  hipMemsetAsync(cursor, 0, (size_t)N_NODES * 4, stream);

  k_detect<<<1, 256, 0, stream>>>((const uint*)x, ei, batch, flags);
  k_bn_stats<<<512, 256, 0, stream>>>(x, flags, stats);
  k_prep<<<1, 128, 0, stream>>>(stats, gamma, beta, W, flags, Wp, bp);
  k_gemm<<<(N_NODES + 127) / 128, 256, 0, stream>>>(x, Wp, bp, att_s, att_d, flags, h8, a_src16, a_dst16);
  k_deg<<<1024, 256, 0, stream>>>(ei, flags, deg);
  k_scan1<<<(NCHUNK + 255) / 256, 256, 0, stream>>>(deg, chunk);
  k_scan2<<<1, 1024, 0, stream>>>(chunk);
  k_scan3<<<(NCHUNK + 255) / 256, 256, 0, stream>>>(deg, chunk, offsets);
  k_scatter<<<1024, 256, 0, stream>>>(ei, flags, offsets, cursor, csr);
  k_msg<<<N_NODES / 4, 256, 0, stream>>>(offsets, csr, a_src16, a_dst16, (const ushort*)h8, bias, flags, out_n);
  k_pool<<<N_G, 256, 0, stream>>>(out_n, batch, flags, (float*)d_out);
}

// Round 3
// 387.118 us; speedup vs baseline: 2.9134x; 1.3689x over previous
//
#include <hip/hip_runtime.h>
#include <hip/hip_bf16.h>
#include <hip/hip_fp16.h>

// GAT fused pipeline for MI355X.
// R13: R12 confirmed atomic serialization (1048->530us). New top kernel:
// k_scatter 112us with WRITE_SIZE=110MB for a 6.8MB csr -> scattered 4B
// stores dirty whole 64B lines that bounce between non-coherent per-XCD L2s
// (1.7M x 64B = 109MB, matches). k_deg has the same disease.
// Fix: 2-level bucket scatter. binA: LDS histogram of dst>>9 (196 buckets).
// binscan: scan -> bucket offsets. binB: per-block contiguous runs of packed
// (src<<9|dst&511) 4B entries (write ~7MB). binC: one block per bucket,
// LDS degree count + scan -> offsets[] (sequential) + csr scatter confined
// to a 35KB single-CU region (each line evicted once).
// k_deg / k_scan1/2/3 / k_scatter deleted.
// Prediction: CSR build 160us -> 30-40us; total 530 -> ~400-430us.

#define N_NODES 100000
#define N_EDGE  1600000
#define N_ET    1700000   // edges + self-loops
#define N_G     100
#define HEADS   8
#define OUTC    16
#define EPS     1e-5f
#define NEG     0.2f
#define NB_BUCKETS 196    // ceil(100000 / 512)
#define EPB     6641      // ceil(N_ET / 256 blocks)

typedef unsigned int uint;
typedef unsigned short ushort;
typedef float f32x2 __attribute__((ext_vector_type(2)));

__device__ __forceinline__ float bf2f_lo(uint u){ union{uint i; float f;} c; c.i = u << 16; return c.f; }
__device__ __forceinline__ float bf2f_hi(uint u){ union{uint i; float f;} c; c.i = u & 0xffff0000u; return c.f; }
__device__ __forceinline__ float bf2f(ushort u){ union{uint i; float f;} c; c.i = ((uint)u) << 16; return c.f; }
__device__ __forceinline__ float scrub(float v){ return (v == v) ? v : 0.f; }

__device__ __forceinline__ float ldf(const void* p, int i, int f32){
  return f32 ? ((const float*)p)[i] : bf2f(((const ushort*)p)[i]);
}
__device__ __forceinline__ int ldid(const int* p, int flat, int is64){
  return is64 ? p[2 * flat] : p[flat];
}

// ---------------- dtype detection ----------------
__global__ void k_detect(const uint* __restrict__ x32, const int* __restrict__ ei32,
                         const int* __restrict__ b32, int* __restrict__ flags){
  __shared__ int cnt[3];
  int t = threadIdx.x;
  if (t < 3) cnt[t] = 0;
  __syncthreads();
  { uint w = x32[t]; uint el = (w >> 7) & 0xffu;
    if (el != 0 && (el < 110 || el > 140)) atomicAdd(&cnt[0], 1); }
  if (t < 128){ if (ei32[2 * t + 1] != 0) atomicAdd(&cnt[1], 1); }
  if (t < 128){ if (b32[98001 + 2 * t] != 0) atomicAdd(&cnt[2], 1); }
  __syncthreads();
  if (t == 0){
    flags[0] = cnt[0] > 64;  // 1 = floats are fp32
    flags[1] = cnt[1] < 32;  // 1 = edge_index is int64
    flags[2] = cnt[2] < 32;  // 1 = batch is int64
    flags[3] = 0;
  }
}

// ---------------- BN statistics: column sum / sumsq ----------------
__global__ __launch_bounds__(256) void k_bn_stats(const void* __restrict__ xraw,
                                                  const int* __restrict__ flags,
                                                  float* __restrict__ stats){
  int f32 = flags[0];
  int t = threadIdx.x;
  int c = t & 63;
  int c0 = c * 2;
  float s0 = 0.f, s1 = 0.f, q0 = 0.f, q1 = 0.f;
  if (f32){
    const float2* x2 = (const float2*)xraw;
    for (int r = blockIdx.x * 4 + (t >> 6); r < N_NODES; r += gridDim.x * 4){
      float2 v = x2[r * 64 + c];
      float f0 = scrub(v.x), f1 = scrub(v.y);
      s0 += f0; q0 += f0 * f0;
      s1 += f1; q1 += f1 * f1;
    }
  } else {
    const uint* x2 = (const uint*)xraw;
    for (int r = blockIdx.x * 4 + (t >> 6); r < N_NODES; r += gridDim.x * 4){
      uint v = x2[r * 64 + c];
      float f0 = scrub(bf2f_lo(v)), f1 = scrub(bf2f_hi(v));
      s0 += f0; q0 += f0 * f0;
      s1 += f1; q1 += f1 * f1;
    }
  }
  __shared__ float red[4][256];
  red[0][t] = s0; red[1][t] = q0; red[2][t] = s1; red[3][t] = q1;
  __syncthreads();
  if (t < 64){
    s0 = red[0][t] + red[0][t+64] + red[0][t+128] + red[0][t+192];
    q0 = red[1][t] + red[1][t+64] + red[1][t+128] + red[1][t+192];
    s1 = red[2][t] + red[2][t+64] + red[2][t+128] + red[2][t+192];
    q1 = red[3][t] + red[3][t+64] + red[3][t+128] + red[3][t+192];
    atomicAdd(&stats[c0],       s0);
    atomicAdd(&stats[c0+1],     s1);
    atomicAdd(&stats[128+c0],   q0);
    atomicAdd(&stats[128+c0+1], q1);
  }
}

// ------------- fold BN into GEMM: Wp = scale*W, bp = shift @ W ---------------
__global__ __launch_bounds__(128) void k_prep(const float* __restrict__ stats,
                                              const void* __restrict__ gamma,
                                              const void* __restrict__ beta,
                                              const void* __restrict__ W,
                                              const int* __restrict__ flags,
                                              float* __restrict__ Wp, float* __restrict__ bp){
  int f32 = flags[0];
  __shared__ float scl[128], shf[128];
  int t = threadIdx.x;
  float mean = scrub(stats[t] * (1.0f / N_NODES));
  float var  = stats[128 + t] * (1.0f / N_NODES) - mean * mean;
  if (!(var > 0.f)) var = 0.f;
  float sc = scrub(ldf(gamma, t, f32)) * rsqrtf(var + EPS);
  sc = scrub(sc);
  scl[t] = sc;
  shf[t] = scrub(scrub(ldf(beta, t, f32)) - mean * sc);
  __syncthreads();
  float b = 0.f;
  for (int c = 0; c < 128; c++){
    float w = scrub(ldf(W, c * 128 + t, f32));
    Wp[c * 128 + t] = scl[c] * w;
    b += shf[c] * w;
  }
  bp[t] = scrub(b);
}

// -------- GEMM h = x @ Wp + bp -> fp8 h8 [N][128B] + fused attn scalars ------
__global__ __launch_bounds__(256) void k_gemm(const void* __restrict__ xraw,
                                              const float* __restrict__ Wp,
                                              const float* __restrict__ bp,
                                              const void* __restrict__ att_src,
                                              const void* __restrict__ att_dst,
                                              const int* __restrict__ flags,
                                              unsigned char* __restrict__ h8,
                                              __half* __restrict__ a_src16,
                                              __half* __restrict__ a_dst16){
  int f32 = flags[0];
  __shared__ float As[8][132];
  __shared__ float Bs[8][132];
  __shared__ float sS[128], sD[128];
  int t = threadIdx.x;
  int tx = t & 15, ty = t >> 4;
  if (t < 128){ sS[t] = scrub(ldf(att_src, t, f32)); sD[t] = scrub(ldf(att_dst, t, f32)); }
  int row0 = blockIdx.x * 128;
  float acc[8][8];
#pragma unroll
  for (int i = 0; i < 8; i++)
#pragma unroll
    for (int u = 0; u < 8; u++) acc[i][u] = 0.f;

  int ar = t >> 1, ak = (t & 1) * 4;
  int bk = t >> 5, bj = (t & 31) * 4;
  for (int k0 = 0; k0 < 128; k0 += 8){
    int grow = row0 + ar;
    float a0v = 0.f, a1v = 0.f, a2v = 0.f, a3v = 0.f;
    if (grow < N_NODES){
      if (f32){
        float4 r4 = *(const float4*)((const float*)xraw + (size_t)grow * 128 + k0 + ak);
        a0v = scrub(r4.x); a1v = scrub(r4.y); a2v = scrub(r4.z); a3v = scrub(r4.w);
      } else {
        uint2 raw = *(const uint2*)((const ushort*)xraw + (size_t)grow * 128 + k0 + ak);
        a0v = scrub(bf2f_lo(raw.x)); a1v = scrub(bf2f_hi(raw.x));
        a2v = scrub(bf2f_lo(raw.y)); a3v = scrub(bf2f_hi(raw.y));
      }
    }
    As[ak+0][ar] = a0v; As[ak+1][ar] = a1v; As[ak+2][ar] = a2v; As[ak+3][ar] = a3v;
    float4 wb = *(const float4*)(Wp + (k0 + bk) * 128 + bj);
    *(float4*)&Bs[bk][bj] = wb;
    __syncthreads();
#pragma unroll
    for (int k = 0; k < 8; k++){
      float4 a0 = *(const float4*)&As[k][ty * 8];
      float4 a1 = *(const float4*)&As[k][ty * 8 + 4];
      float4 b0 = *(const float4*)&Bs[k][tx * 4];
      float4 b1 = *(const float4*)&Bs[k][64 + tx * 4];
      float a[8] = {a0.x,a0.y,a0.z,a0.w,a1.x,a1.y,a1.z,a1.w};
      float b[8] = {b0.x,b0.y,b0.z,b0.w,b1.x,b1.y,b1.z,b1.w};
#pragma unroll
      for (int i = 0; i < 8; i++)
#pragma unroll
        for (int u = 0; u < 8; u++) acc[i][u] += a[i] * b[u];
    }
    __syncthreads();
  }
  float4 bl = *(const float4*)(bp + tx * 4);
  float4 bh = *(const float4*)(bp + 64 + tx * 4);
  float bb[8] = {bl.x,bl.y,bl.z,bl.w,bh.x,bh.y,bh.z,bh.w};
#pragma unroll
  for (int i = 0; i < 8; i++){
    int r = row0 + ty * 8 + i;        // uniform across tx -> shuffle groups safe
    if (r >= N_NODES) break;
    float o[8];
#pragma unroll
    for (int u = 0; u < 8; u++){
      float v = scrub(acc[i][u] + bb[u]);
      o[u] = fminf(fmaxf(v, -448.f), 448.f);   // e4m3 sat guard (values << 448)
    }
    uint w0 = __builtin_amdgcn_cvt_pk_fp8_f32(o[0], o[1], 0, false);
    w0 = __builtin_amdgcn_cvt_pk_fp8_f32(o[2], o[3], (int)w0, true);
    uint w1 = __builtin_amdgcn_cvt_pk_fp8_f32(o[4], o[5], 0, false);
    w1 = __builtin_amdgcn_cvt_pk_fp8_f32(o[6], o[7], (int)w1, true);
    unsigned char* po = h8 + (size_t)r * 128;
    *(uint*)(po + tx * 4)      = w0;
    *(uint*)(po + 64 + tx * 4) = w1;
    float pa = 0.f, pb = 0.f, qa = 0.f, qb = 0.f;
#pragma unroll
    for (int u = 0; u < 4; u++){
      pa += o[u]     * sS[tx * 4 + u];
      qa += o[u]     * sD[tx * 4 + u];
      pb += o[u + 4] * sS[64 + tx * 4 + u];
      qb += o[u + 4] * sD[64 + tx * 4 + u];
    }
    pa += __shfl_xor(pa, 1); pa += __shfl_xor(pa, 2);
    pb += __shfl_xor(pb, 1); pb += __shfl_xor(pb, 2);
    qa += __shfl_xor(qa, 1); qa += __shfl_xor(qa, 2);
    qb += __shfl_xor(qb, 1); qb += __shfl_xor(qb, 2);
    if ((tx & 3) == 0){
      int hA = tx >> 2;
      a_src16[(size_t)r * 8 + hA]     = __float2half_rn(scrub(pa));
      a_src16[(size_t)r * 8 + 4 + hA] = __float2half_rn(scrub(pb));
      a_dst16[(size_t)r * 8 + hA]     = __float2half_rn(scrub(qa));
      a_dst16[(size_t)r * 8 + 4 + hA] = __float2half_rn(scrub(qb));
    }
  }
}

// --------------------- CSR build: 2-level bucket scatter ---------------------
// bucket b = dst >> 9 (512 nodes / bucket, NB_BUCKETS = 196).

// pass A: global bucket histogram (LDS hist -> 1 atomic per bucket per block)
__global__ __launch_bounds__(256) void k_binA(const int* __restrict__ ei,
                                              const int* __restrict__ flags,
                                              int* __restrict__ bcnt){
  int is64 = flags[1];
  __shared__ int hist[NB_BUCKETS];
  int t = threadIdx.x;
  for (int i = t; i < NB_BUCKETS; i += 256) hist[i] = 0;
  __syncthreads();
  int e0 = blockIdx.x * EPB, e1 = min(e0 + EPB, N_ET);
  for (int e = e0 + t; e < e1; e += 256){
    int d = (e < N_EDGE) ? ldid(ei, N_EDGE + e, is64) : (e - N_EDGE);
    uint b = (uint)d >> 9; if (b >= NB_BUCKETS) b = NB_BUCKETS - 1;
    atomicAdd(&hist[b], 1);
  }
  __syncthreads();
  for (int i = t; i < NB_BUCKETS; i += 256)
    if (hist[i]) atomicAdd(&bcnt[i], hist[i]);
}

// scan bucket counts -> boff (exclusive), bcur (cursor copy), offsets[N]=N_ET
__global__ __launch_bounds__(256) void k_binscan(const int* __restrict__ bcnt,
                                                 int* __restrict__ boff,
                                                 int* __restrict__ bcur,
                                                 int* __restrict__ offsets){
  __shared__ int sd[256];
  int t = threadIdx.x;
  int v = (t < NB_BUCKETS) ? bcnt[t] : 0;
  sd[t] = v;
  __syncthreads();
  for (int off = 1; off < 256; off <<= 1){
    int add = (t >= off) ? sd[t - off] : 0;
    __syncthreads();
    sd[t] += add;
    __syncthreads();
  }
  int incl = sd[t];
  if (t < NB_BUCKETS){ int ex = incl - v; boff[t] = ex; bcur[t] = ex; }
  if (t == NB_BUCKETS - 1){ boff[NB_BUCKETS] = incl; offsets[N_NODES] = incl; }
}

// pass B: bin edges into bucket runs; entry = (src<<9) | (dst & 511), 4B.
// Per-block contiguous runs -> write-combining friendly (~7MB total writes).
__global__ __launch_bounds__(256) void k_binB(const int* __restrict__ ei,
                                              const int* __restrict__ flags,
                                              int* __restrict__ bcur,
                                              uint* __restrict__ pairBuf){
  int is64 = flags[1];
  __shared__ int hist[NB_BUCKETS];
  __shared__ int base[NB_BUCKETS];
  int t = threadIdx.x;
  for (int i = t; i < NB_BUCKETS; i += 256) hist[i] = 0;
  __syncthreads();
  int e0 = blockIdx.x * EPB, e1 = min(e0 + EPB, N_ET);
  for (int e = e0 + t; e < e1; e += 256){
    int d = (e < N_EDGE) ? ldid(ei, N_EDGE + e, is64) : (e - N_EDGE);
    uint b = (uint)d >> 9; if (b >= NB_BUCKETS) b = NB_BUCKETS - 1;
    atomicAdd(&hist[b], 1);
  }
  __syncthreads();
  for (int i = t; i < NB_BUCKETS; i += 256){
    int c = hist[i];
    base[i] = c ? atomicAdd(&bcur[i], c) : 0;
    hist[i] = 0;               // reuse as local cursor
  }
  __syncthreads();
  for (int e = e0 + t; e < e1; e += 256){
    int s, d;
    if (e < N_EDGE){ s = ldid(ei, e, is64); d = ldid(ei, N_EDGE + e, is64); }
    else { s = d = e - N_EDGE; }
    uint b = (uint)d >> 9; if (b >= NB_BUCKETS) b = NB_BUCKETS - 1;
    int pos = atomicAdd(&hist[b], 1);
    pairBuf[base[b] + pos] = ((uint)s << 9) | ((uint)d & 511u);
  }
}

// pass C: one block per bucket. LDS degree count + scan -> offsets (sequential
// store); LDS cursors scatter csr within the bucket's ~35KB region (1 CU).
__global__ __launch_bounds__(512) void k_binC(const uint* __restrict__ pairBuf,
                                              const int* __restrict__ boff,
                                              int* __restrict__ offsets,
                                              int* __restrict__ csr){
  int b = blockIdx.x, t = threadIdx.x;
  __shared__ int degL[512];
  __shared__ int offL[512];
  __shared__ int curL[512];
  degL[t] = 0;
  __syncthreads();
  int p0 = boff[b], p1 = boff[b + 1];
  for (int i = p0 + t; i < p1; i += 512)
    atomicAdd(&degL[pairBuf[i] & 511u], 1);
  __syncthreads();
  int v = degL[t];
  offL[t] = v;
  __syncthreads();
  for (int off = 1; off < 512; off <<= 1){
    int add = (t >= off) ? offL[t - off] : 0;
    __syncthreads();
    offL[t] += add;
    __syncthreads();
  }
  int excl = offL[t] - v;
  int node = (b << 9) + t;
  if (node < N_NODES) offsets[node] = p0 + excl;
  offL[t] = excl;              // own-entry rewrite, no cross-read hazard
  curL[t] = 0;
  __syncthreads();
  for (int i = p0 + t; i < p1; i += 512){
    uint e = pairBuf[i];
    int dl = e & 511u;
    int s  = e >> 9;
    int pos = atomicAdd(&curL[dl], 1);
    csr[p0 + offL[dl] + pos] = s;
  }
}

// ------ fused: inline softmax + fp8 gather + head-mean + ELU -> out_n.
__global__ __launch_bounds__(256) void k_msg(const int* __restrict__ offsets, const int* __restrict__ csr,
                                             const __half* __restrict__ a_src16, const __half* __restrict__ a_dst16,
                                             const ushort* __restrict__ h8, const void* __restrict__ bias,
                                             const int* __restrict__ flags,
                                             float* __restrict__ out_n){
  int f32 = flags[0];
  int t = threadIdx.x;
  int wv = t >> 6, lane = t & 63;
  int n = blockIdx.x * 4 + wv;        // grid = N/4 exactly
  int myh = lane >> 3;
  int start = offsets[n], end = offsets[n + 1];
  float ad = __half2float(a_dst16[(size_t)n * 8 + myh]);
  const ushort* as16 = (const ushort*)a_src16;
  float acc0 = 0.f, acc1 = 0.f, den = 0.f;

  for (int base = start; base < end; base += 64){
    int cnt = min(64, end - base);
    int sreg = csr[min(base + lane, N_ET - 1)];
    int jj = 0;
    for (; jj + 8 <= cnt; jj += 8){
      int s0 = __shfl(sreg, jj);
      int s1 = __shfl(sreg, jj + 1);
      int s2 = __shfl(sreg, jj + 2);
      int s3 = __shfl(sreg, jj + 3);
      int s4 = __shfl(sreg, jj + 4);
      int s5 = __shfl(sreg, jj + 5);
      int s6 = __shfl(sreg, jj + 6);
      int s7 = __shfl(sreg, jj + 7);
      ushort h0 = h8[(size_t)s0 * 64 + lane];
      ushort h1 = h8[(size_t)s1 * 64 + lane];
      ushort h2 = h8[(size_t)s2 * 64 + lane];
      ushort h3 = h8[(size_t)s3 * 64 + lane];
      ushort h4 = h8[(size_t)s4 * 64 + lane];
      ushort h5 = h8[(size_t)s5 * 64 + lane];
      ushort h6 = h8[(size_t)s6 * 64 + lane];
      ushort h7 = h8[(size_t)s7 * 64 + lane];
      ushort a0 = as16[(size_t)s0 * 8 + myh];
      ushort a1 = as16[(size_t)s1 * 8 + myh];
      ushort a2 = as16[(size_t)s2 * 8 + myh];
      ushort a3 = as16[(size_t)s3 * 8 + myh];
      ushort a4 = as16[(size_t)s4 * 8 + myh];
      ushort a5 = as16[(size_t)s5 * 8 + myh];
      ushort a6 = as16[(size_t)s6 * 8 + myh];
      ushort a7 = as16[(size_t)s7 * 8 + myh];
      __builtin_amdgcn_sched_barrier(0);   // all 16 loads issue before math
#define EDGE(AA, HH)                                              \
      { float e = __half2float(*(__half*)&(AA)) + ad;             \
        e = e > 0.f ? e : NEG * e;                                \
        float p = __expf(fminf(e, 30.f));                         \
        f32x2 hv = __builtin_amdgcn_cvt_pk_f32_fp8((int)(HH), false); \
        den += p; acc0 += p * hv[0]; acc1 += p * hv[1]; }
      EDGE(a0, h0) EDGE(a1, h1) EDGE(a2, h2) EDGE(a3, h3)
      EDGE(a4, h4) EDGE(a5, h5) EDGE(a6, h6) EDGE(a7, h7)
#undef EDGE
    }
    for (; jj < cnt; jj++){
      int s0 = __shfl(sreg, jj);
      ushort hh = h8[(size_t)s0 * 64 + lane];
      ushort a0 = as16[(size_t)s0 * 8 + myh];
      float e = __half2float(*(__half*)&a0) + ad;
      e = e > 0.f ? e : NEG * e;
      float p = __expf(fminf(e, 30.f));
      f32x2 hv = __builtin_amdgcn_cvt_pk_f32_fp8((int)hh, false);
      den += p; acc0 += p * hv[0]; acc1 += p * hv[1];
    }
  }

  float inv = (den > 0.f) ? (1.0f / den) : 0.f;   // den>0 via self-loop
  float v0 = acc0 * inv, v1 = acc1 * inv;
  v0 += __shfl_xor(v0, 8);  v1 += __shfl_xor(v1, 8);
  v0 += __shfl_xor(v0, 16); v1 += __shfl_xor(v1, 16);
  v0 += __shfl_xor(v0, 32); v1 += __shfl_xor(v1, 32);
  if (lane < 8){
    int c0 = lane * 2;
    float o0 = v0 * 0.125f + scrub(ldf(bias, c0, f32));
    float o1 = v1 * 0.125f + scrub(ldf(bias, c0 + 1, f32));
    o0 = o0 > 0.f ? o0 : (__expf(o0) - 1.0f);
    o1 = o1 > 0.f ? o1 : (__expf(o1) - 1.0f);
    float2* po = (float2*)(out_n + (size_t)n * 16);
    po[lane] = make_float2(scrub(o0), scrub(o1));   // 64B/wave, no atomics
  }
}

// ---- pool: 1 block per graph. Binary-search sorted batch for the segment,
// segmented fp32 reduce of out_n, divide by count, write d_out directly. ----
__global__ __launch_bounds__(256) void k_pool(const float* __restrict__ out_n,
                                              const int* __restrict__ batch,
                                              const int* __restrict__ flags,
                                              float* __restrict__ out){
  int b64 = flags[2];
  int g = blockIdx.x;                  // N_G blocks
  int t = threadIdx.x;
  int c = t & 15, rg = t >> 4;         // 16 channels x 16 row-groups
  int lo = 0, hi = N_NODES;
  while (lo < hi){ int m = (lo + hi) >> 1; if (ldid(batch, m, b64) < g) lo = m + 1; else hi = m; }
  int lo2 = lo, hi2 = N_NODES;
  while (lo2 < hi2){ int m = (lo2 + hi2) >> 1; if (ldid(batch, m, b64) < g + 1) lo2 = m + 1; else hi2 = m; }
  float acc = 0.f;
  for (int r = lo + rg; r < lo2; r += 16)
    acc += out_n[(size_t)r * 16 + c];
  __shared__ float red[16][17];
  red[rg][c] = acc;
  __syncthreads();
  if (t < 16){
    float v = 0.f;
#pragma unroll
    for (int i = 0; i < 16; i++) v += red[i][t];
    float cntf = (float)(lo2 - lo);
    out[g * 16 + t] = scrub(v / fmaxf(cntf, 1.0f));
  }
}

// -----------------------------------------------------------------------------
extern "C" void kernel_launch(void* const* d_in, const int* in_sizes, int n_in,
                              void* d_out, int out_size, void* d_ws, size_t ws_size,
                              hipStream_t stream){
  (void)in_sizes; (void)n_in; (void)out_size; (void)ws_size;
  const void* x     = d_in[0];
  const int*  ei    = (const int*)d_in[1];
  const int*  batch = (const int*)d_in[2];
  const void* gamma = d_in[3];
  const void* beta  = d_in[4];
  const void* W     = d_in[5];
  const void* att_s = d_in[6];
  const void* att_d = d_in[7];
  const void* bias  = d_in[8];

  // ws total ~36.5 MB (h8 12.8, csr 6.8, pairBuf 6.8, out_n 6.4; <=36.9 proven).
  char* ws = (char*)d_ws;
  size_t off = 0;
  auto alloc = [&](size_t b){ size_t r = off; off += (b + 255) & ~(size_t)255; return r; };
  int*    flags   = (int*)(ws + alloc(4 * 4));
  float*  stats   = (float*)(ws + alloc(256 * 4));
  float*  Wp      = (float*)(ws + alloc(16384 * 4));
  float*  bp      = (float*)(ws + alloc(128 * 4));
  int*    bcnt    = (int*)(ws + alloc(NB_BUCKETS * 4));
  int*    boff    = (int*)(ws + alloc((NB_BUCKETS + 1) * 4));
  int*    bcur    = (int*)(ws + alloc(NB_BUCKETS * 4));
  int*    offsets = (int*)(ws + alloc((size_t)(N_NODES + 1) * 4));
  __half* a_src16 = (__half*)(ws + alloc((size_t)N_NODES * 8 * 2));
  __half* a_dst16 = (__half*)(ws + alloc((size_t)N_NODES * 8 * 2));
  float*  out_n   = (float*)(ws + alloc((size_t)N_NODES * 16 * 4));
  unsigned char* h8 = (unsigned char*)(ws + alloc((size_t)N_NODES * 128));
  uint*   pairBuf = (uint*)(ws + alloc((size_t)N_ET * 4));
  int*    csr     = (int*)(ws + alloc((size_t)N_ET * 4));

  hipMemsetAsync(stats, 0, 256 * 4, stream);
  hipMemsetAsync(bcnt,  0, NB_BUCKETS * 4, stream);

  k_detect<<<1, 256, 0, stream>>>((const uint*)x, ei, batch, flags);
  k_bn_stats<<<512, 256, 0, stream>>>(x, flags, stats);
  k_prep<<<1, 128, 0, stream>>>(stats, gamma, beta, W, flags, Wp, bp);
  k_gemm<<<(N_NODES + 127) / 128, 256, 0, stream>>>(x, Wp, bp, att_s, att_d, flags, h8, a_src16, a_dst16);
  k_binA<<<256, 256, 0, stream>>>(ei, flags, bcnt);
  k_binscan<<<1, 256, 0, stream>>>(bcnt, boff, bcur, offsets);
  k_binB<<<256, 256, 0, stream>>>(ei, flags, bcur, pairBuf);
  k_binC<<<NB_BUCKETS, 512, 0, stream>>>(pairBuf, boff, offsets, csr);
  k_msg<<<N_NODES / 4, 256, 0, stream>>>(offsets, csr, a_src16, a_dst16, (const ushort*)h8, bias, flags, out_n);
  k_pool<<<N_G, 256, 0, stream>>>(out_n, batch, flags, (float*)d_out);
}

// Round 4
// 363.837 us; speedup vs baseline: 3.0998x; 1.0640x over previous
//
#include <hip/hip_runtime.h>
#include <hip/hip_bf16.h>
#include <hip/hip_fp16.h>

// GAT fused pipeline for MI355X.
// R14: R13 made k_msg VALU-issue-bound (VALUBusy 84%, BW 1.58TB/s, 81us).
// Fix 1: 2-edges-per-wave k_msg — each lane owns 4 channels (one 4B fp8
// load), 32 lanes = full row, wave halves process 2 edges at once.
// Loads/edge 2->1, addr math halved, leaky = fmax(e, 0.2e).
// Fix 2: binA+binB merged (one ei pass) with fixed-capacity buckets
// (CAP 9472 = mean 8704 + 8.5 sigma); out_n aliases retired pairBuf.
// Prediction: k_msg 81 -> 50-65us (VALUBusy -> ~50%); if it stays ~80us
// the L2-miss path is the floor -> pivot to k_gemm next.

#define N_NODES 100000
#define N_EDGE  1600000
#define N_ET    1700000   // edges + self-loops
#define N_G     100
#define HEADS   8
#define OUTC    16
#define EPS     1e-5f
#define NEG     0.2f
#define NB_BUCKETS 196    // ceil(100000 / 512)
#define BCAP    9472      // per-bucket capacity (mean 8704, sigma ~90)
#define EPB     6641      // ceil(N_ET / 256 blocks)

typedef unsigned int uint;
typedef unsigned short ushort;
typedef float f32x2 __attribute__((ext_vector_type(2)));

__device__ __forceinline__ float bf2f_lo(uint u){ union{uint i; float f;} c; c.i = u << 16; return c.f; }
__device__ __forceinline__ float bf2f_hi(uint u){ union{uint i; float f;} c; c.i = u & 0xffff0000u; return c.f; }
__device__ __forceinline__ float bf2f(ushort u){ union{uint i; float f;} c; c.i = ((uint)u) << 16; return c.f; }
__device__ __forceinline__ float scrub(float v){ return (v == v) ? v : 0.f; }

__device__ __forceinline__ float ldf(const void* p, int i, int f32){
  return f32 ? ((const float*)p)[i] : bf2f(((const ushort*)p)[i]);
}
__device__ __forceinline__ int ldid(const int* p, int flat, int is64){
  return is64 ? p[2 * flat] : p[flat];
}

// ---------------- dtype detection ----------------
__global__ void k_detect(const uint* __restrict__ x32, const int* __restrict__ ei32,
                         const int* __restrict__ b32, int* __restrict__ flags){
  __shared__ int cnt[3];
  int t = threadIdx.x;
  if (t < 3) cnt[t] = 0;
  __syncthreads();
  { uint w = x32[t]; uint el = (w >> 7) & 0xffu;
    if (el != 0 && (el < 110 || el > 140)) atomicAdd(&cnt[0], 1); }
  if (t < 128){ if (ei32[2 * t + 1] != 0) atomicAdd(&cnt[1], 1); }
  if (t < 128){ if (b32[98001 + 2 * t] != 0) atomicAdd(&cnt[2], 1); }
  __syncthreads();
  if (t == 0){
    flags[0] = cnt[0] > 64;  // 1 = floats are fp32
    flags[1] = cnt[1] < 32;  // 1 = edge_index is int64
    flags[2] = cnt[2] < 32;  // 1 = batch is int64
    flags[3] = 0;
  }
}

// ---------------- BN statistics: column sum / sumsq ----------------
__global__ __launch_bounds__(256) void k_bn_stats(const void* __restrict__ xraw,
                                                  const int* __restrict__ flags,
                                                  float* __restrict__ stats){
  int f32 = flags[0];
  int t = threadIdx.x;
  int c = t & 63;
  int c0 = c * 2;
  float s0 = 0.f, s1 = 0.f, q0 = 0.f, q1 = 0.f;
  if (f32){
    const float2* x2 = (const float2*)xraw;
    for (int r = blockIdx.x * 4 + (t >> 6); r < N_NODES; r += gridDim.x * 4){
      float2 v = x2[r * 64 + c];
      float f0 = scrub(v.x), f1 = scrub(v.y);
      s0 += f0; q0 += f0 * f0;
      s1 += f1; q1 += f1 * f1;
    }
  } else {
    const uint* x2 = (const uint*)xraw;
    for (int r = blockIdx.x * 4 + (t >> 6); r < N_NODES; r += gridDim.x * 4){
      uint v = x2[r * 64 + c];
      float f0 = scrub(bf2f_lo(v)), f1 = scrub(bf2f_hi(v));
      s0 += f0; q0 += f0 * f0;
      s1 += f1; q1 += f1 * f1;
    }
  }
  __shared__ float red[4][256];
  red[0][t] = s0; red[1][t] = q0; red[2][t] = s1; red[3][t] = q1;
  __syncthreads();
  if (t < 64){
    s0 = red[0][t] + red[0][t+64] + red[0][t+128] + red[0][t+192];
    q0 = red[1][t] + red[1][t+64] + red[1][t+128] + red[1][t+192];
    s1 = red[2][t] + red[2][t+64] + red[2][t+128] + red[2][t+192];
    q1 = red[3][t] + red[3][t+64] + red[3][t+128] + red[3][t+192];
    atomicAdd(&stats[c0],       s0);
    atomicAdd(&stats[c0+1],     s1);
    atomicAdd(&stats[128+c0],   q0);
    atomicAdd(&stats[128+c0+1], q1);
  }
}

// ------------- fold BN into GEMM: Wp = scale*W, bp = shift @ W ---------------
__global__ __launch_bounds__(128) void k_prep(const float* __restrict__ stats,
                                              const void* __restrict__ gamma,
                                              const void* __restrict__ beta,
                                              const void* __restrict__ W,
                                              const int* __restrict__ flags,
                                              float* __restrict__ Wp, float* __restrict__ bp){
  int f32 = flags[0];
  __shared__ float scl[128], shf[128];
  int t = threadIdx.x;
  float mean = scrub(stats[t] * (1.0f / N_NODES));
  float var  = stats[128 + t] * (1.0f / N_NODES) - mean * mean;
  if (!(var > 0.f)) var = 0.f;
  float sc = scrub(ldf(gamma, t, f32)) * rsqrtf(var + EPS);
  sc = scrub(sc);
  scl[t] = sc;
  shf[t] = scrub(scrub(ldf(beta, t, f32)) - mean * sc);
  __syncthreads();
  float b = 0.f;
  for (int c = 0; c < 128; c++){
    float w = scrub(ldf(W, c * 128 + t, f32));
    Wp[c * 128 + t] = scl[c] * w;
    b += shf[c] * w;
  }
  bp[t] = scrub(b);
}

// -------- GEMM h = x @ Wp + bp -> fp8 h8 [N][128B] + fused attn scalars ------
__global__ __launch_bounds__(256) void k_gemm(const void* __restrict__ xraw,
                                              const float* __restrict__ Wp,
                                              const float* __restrict__ bp,
                                              const void* __restrict__ att_src,
                                              const void* __restrict__ att_dst,
                                              const int* __restrict__ flags,
                                              unsigned char* __restrict__ h8,
                                              __half* __restrict__ a_src16,
                                              __half* __restrict__ a_dst16){
  int f32 = flags[0];
  __shared__ float As[8][132];
  __shared__ float Bs[8][132];
  __shared__ float sS[128], sD[128];
  int t = threadIdx.x;
  int tx = t & 15, ty = t >> 4;
  if (t < 128){ sS[t] = scrub(ldf(att_src, t, f32)); sD[t] = scrub(ldf(att_dst, t, f32)); }
  int row0 = blockIdx.x * 128;
  float acc[8][8];
#pragma unroll
  for (int i = 0; i < 8; i++)
#pragma unroll
    for (int u = 0; u < 8; u++) acc[i][u] = 0.f;

  int ar = t >> 1, ak = (t & 1) * 4;
  int bk = t >> 5, bj = (t & 31) * 4;
  for (int k0 = 0; k0 < 128; k0 += 8){
    int grow = row0 + ar;
    float a0v = 0.f, a1v = 0.f, a2v = 0.f, a3v = 0.f;
    if (grow < N_NODES){
      if (f32){
        float4 r4 = *(const float4*)((const float*)xraw + (size_t)grow * 128 + k0 + ak);
        a0v = scrub(r4.x); a1v = scrub(r4.y); a2v = scrub(r4.z); a3v = scrub(r4.w);
      } else {
        uint2 raw = *(const uint2*)((const ushort*)xraw + (size_t)grow * 128 + k0 + ak);
        a0v = scrub(bf2f_lo(raw.x)); a1v = scrub(bf2f_hi(raw.x));
        a2v = scrub(bf2f_lo(raw.y)); a3v = scrub(bf2f_hi(raw.y));
      }
    }
    As[ak+0][ar] = a0v; As[ak+1][ar] = a1v; As[ak+2][ar] = a2v; As[ak+3][ar] = a3v;
    float4 wb = *(const float4*)(Wp + (k0 + bk) * 128 + bj);
    *(float4*)&Bs[bk][bj] = wb;
    __syncthreads();
#pragma unroll
    for (int k = 0; k < 8; k++){
      float4 a0 = *(const float4*)&As[k][ty * 8];
      float4 a1 = *(const float4*)&As[k][ty * 8 + 4];
      float4 b0 = *(const float4*)&Bs[k][tx * 4];
      float4 b1 = *(const float4*)&Bs[k][64 + tx * 4];
      float a[8] = {a0.x,a0.y,a0.z,a0.w,a1.x,a1.y,a1.z,a1.w};
      float b[8] = {b0.x,b0.y,b0.z,b0.w,b1.x,b1.y,b1.z,b1.w};
#pragma unroll
      for (int i = 0; i < 8; i++)
#pragma unroll
        for (int u = 0; u < 8; u++) acc[i][u] += a[i] * b[u];
    }
    __syncthreads();
  }
  float4 bl = *(const float4*)(bp + tx * 4);
  float4 bh = *(const float4*)(bp + 64 + tx * 4);
  float bb[8] = {bl.x,bl.y,bl.z,bl.w,bh.x,bh.y,bh.z,bh.w};
#pragma unroll
  for (int i = 0; i < 8; i++){
    int r = row0 + ty * 8 + i;        // uniform across tx -> shuffle groups safe
    if (r >= N_NODES) break;
    float o[8];
#pragma unroll
    for (int u = 0; u < 8; u++){
      float v = scrub(acc[i][u] + bb[u]);
      o[u] = fminf(fmaxf(v, -448.f), 448.f);   // e4m3 sat guard (values << 448)
    }
    uint w0 = __builtin_amdgcn_cvt_pk_fp8_f32(o[0], o[1], 0, false);
    w0 = __builtin_amdgcn_cvt_pk_fp8_f32(o[2], o[3], (int)w0, true);
    uint w1 = __builtin_amdgcn_cvt_pk_fp8_f32(o[4], o[5], 0, false);
    w1 = __builtin_amdgcn_cvt_pk_fp8_f32(o[6], o[7], (int)w1, true);
    unsigned char* po = h8 + (size_t)r * 128;
    *(uint*)(po + tx * 4)      = w0;
    *(uint*)(po + 64 + tx * 4) = w1;
    float pa = 0.f, pb = 0.f, qa = 0.f, qb = 0.f;
#pragma unroll
    for (int u = 0; u < 4; u++){
      pa += o[u]     * sS[tx * 4 + u];
      qa += o[u]     * sD[tx * 4 + u];
      pb += o[u + 4] * sS[64 + tx * 4 + u];
      qb += o[u + 4] * sD[64 + tx * 4 + u];
    }
    pa += __shfl_xor(pa, 1); pa += __shfl_xor(pa, 2);
    pb += __shfl_xor(pb, 1); pb += __shfl_xor(pb, 2);
    qa += __shfl_xor(qa, 1); qa += __shfl_xor(qa, 2);
    qb += __shfl_xor(qb, 1); qb += __shfl_xor(qb, 2);
    if ((tx & 3) == 0){
      int hA = tx >> 2;
      a_src16[(size_t)r * 8 + hA]     = __float2half_rn(scrub(pa));
      a_src16[(size_t)r * 8 + 4 + hA] = __float2half_rn(scrub(pb));
      a_dst16[(size_t)r * 8 + hA]     = __float2half_rn(scrub(qa));
      a_dst16[(size_t)r * 8 + 4 + hA] = __float2half_rn(scrub(qb));
    }
  }
}

// --------------------- CSR build: 2-level bucket scatter ---------------------
// bucket b = dst >> 9 (512 nodes / bucket). Fixed-capacity runs (BCAP).

// merged pass A+B: LDS histogram -> one global cursor grab per bucket ->
// write packed (src<<9 | dst&511) into bucket-run region b*BCAP.
__global__ __launch_bounds__(256) void k_binAB(const int* __restrict__ ei,
                                               const int* __restrict__ flags,
                                               int* __restrict__ bcnt,
                                               uint* __restrict__ pairBuf){
  int is64 = flags[1];
  __shared__ int hist[NB_BUCKETS];
  __shared__ int base[NB_BUCKETS];
  int t = threadIdx.x;
  for (int i = t; i < NB_BUCKETS; i += 256) hist[i] = 0;
  __syncthreads();
  int e0 = blockIdx.x * EPB, e1 = min(e0 + EPB, N_ET);
  for (int e = e0 + t; e < e1; e += 256){
    int d = (e < N_EDGE) ? ldid(ei, N_EDGE + e, is64) : (e - N_EDGE);
    uint b = (uint)d >> 9; if (b >= NB_BUCKETS) b = NB_BUCKETS - 1;
    atomicAdd(&hist[b], 1);
  }
  __syncthreads();
  for (int i = t; i < NB_BUCKETS; i += 256){
    int c = hist[i];
    base[i] = c ? atomicAdd(&bcnt[i], c) : 0;
    hist[i] = 0;               // reuse as local cursor
  }
  __syncthreads();
  for (int e = e0 + t; e < e1; e += 256){
    int s, d;
    if (e < N_EDGE){ s = ldid(ei, e, is64); d = ldid(ei, N_EDGE + e, is64); }
    else { s = d = e - N_EDGE; }
    uint b = (uint)d >> 9; if (b >= NB_BUCKETS) b = NB_BUCKETS - 1;
    int pos = base[b] + atomicAdd(&hist[b], 1);
    if ((uint)pos < BCAP) pairBuf[(size_t)b * BCAP + pos] = ((uint)s << 9) | ((uint)d & 511u);
  }
}

// scan final bucket counts -> boff (exclusive); offsets[N]=total
__global__ __launch_bounds__(256) void k_binscan(const int* __restrict__ bcnt,
                                                 int* __restrict__ boff,
                                                 int* __restrict__ offsets){
  __shared__ int sd[256];
  int t = threadIdx.x;
  int v = (t < NB_BUCKETS) ? min(bcnt[t], BCAP) : 0;
  sd[t] = v;
  __syncthreads();
  for (int off = 1; off < 256; off <<= 1){
    int add = (t >= off) ? sd[t - off] : 0;
    __syncthreads();
    sd[t] += add;
    __syncthreads();
  }
  int incl = sd[t];
  if (t < NB_BUCKETS) boff[t] = incl - v;
  if (t == NB_BUCKETS - 1){ boff[NB_BUCKETS] = incl; offsets[N_NODES] = incl; }
}

// pass C: one block per bucket. LDS degree count + scan -> offsets (sequential
// store); LDS cursors scatter csr within the bucket's ~35KB region (1 CU).
__global__ __launch_bounds__(512) void k_binC(const uint* __restrict__ pairBuf,
                                              const int* __restrict__ bcnt,
                                              const int* __restrict__ boff,
                                              int* __restrict__ offsets,
                                              int* __restrict__ csr){
  int b = blockIdx.x, t = threadIdx.x;
  __shared__ int degL[512];
  __shared__ int offL[512];
  __shared__ int curL[512];
  degL[t] = 0;
  __syncthreads();
  int cnt = min(bcnt[b], BCAP);
  int gbase = boff[b];
  const uint* run = pairBuf + (size_t)b * BCAP;
  for (int i = t; i < cnt; i += 512)
    atomicAdd(&degL[run[i] & 511u], 1);
  __syncthreads();
  int v = degL[t];
  offL[t] = v;
  __syncthreads();
  for (int off = 1; off < 512; off <<= 1){
    int add = (t >= off) ? offL[t - off] : 0;
    __syncthreads();
    offL[t] += add;
    __syncthreads();
  }
  int excl = offL[t] - v;
  int node = (b << 9) + t;
  if (node < N_NODES) offsets[node] = gbase + excl;
  offL[t] = excl;              // own-entry rewrite, no cross-read hazard
  curL[t] = 0;
  __syncthreads();
  for (int i = t; i < cnt; i += 512){
    uint e = run[i];
    int dl = e & 511u;
    int s  = e >> 9;
    int pos = atomicAdd(&curL[dl], 1);
    csr[gbase + offL[dl] + pos] = s;
  }
}

// ------ fused: inline softmax + fp8 gather + head-mean + ELU -> out_n.
// R14: one wave per node; lane owns 4 channels (li=lane&31 -> ch li*4..+3,
// head myh=li>>2); wave halves process 2 edges simultaneously.
__global__ __launch_bounds__(256) void k_msg(const int* __restrict__ offsets, const int* __restrict__ csr,
                                             const __half* __restrict__ a_src16, const __half* __restrict__ a_dst16,
                                             const uint* __restrict__ h32, const void* __restrict__ bias,
                                             const int* __restrict__ flags,
                                             float* __restrict__ out_n){
  int f32 = flags[0];
  int t = threadIdx.x;
  int wv = t >> 6, lane = t & 63;
  int half = lane >> 5, li = lane & 31;
  int myh = li >> 2;
  int n = blockIdx.x * 4 + wv;        // grid = N/4 exactly
  int start = offsets[n], end = offsets[n + 1];
  float ad = __half2float(a_dst16[(size_t)n * 8 + myh]);
  const ushort* as16 = (const ushort*)a_src16;
  float acc0 = 0.f, acc1 = 0.f, acc2 = 0.f, acc3 = 0.f, den = 0.f;

#define PAIR(AA, HH)                                                  \
  { float e = __half2float(*(__half*)&(AA)) + ad;                     \
    e = fmaxf(e, NEG * e);                                            \
    float p = __expf(fminf(e, 30.f));                                 \
    f32x2 lo = __builtin_amdgcn_cvt_pk_f32_fp8((int)(HH), false);     \
    f32x2 hi = __builtin_amdgcn_cvt_pk_f32_fp8((int)(HH), true);      \
    den += p; acc0 += p * lo[0]; acc1 += p * lo[1];                   \
    acc2 += p * hi[0]; acc3 += p * hi[1]; }

  for (int base = start; base < end; base += 64){
    int cnt = min(64, end - base);
    int sreg = csr[min(base + lane, N_ET - 1)];
    int npair = cnt >> 1;
    int jj = 0;
    for (; jj + 4 <= npair; jj += 4){
      int i0 = 2 * jj + half;
      int s0 = __shfl(sreg, i0);
      int s1 = __shfl(sreg, i0 + 2);
      int s2 = __shfl(sreg, i0 + 4);
      int s3 = __shfl(sreg, i0 + 6);
      uint h0 = h32[(uint)s0 * 32u + li];
      uint h1 = h32[(uint)s1 * 32u + li];
      uint h2 = h32[(uint)s2 * 32u + li];
      uint h3 = h32[(uint)s3 * 32u + li];
      ushort a0 = as16[(uint)s0 * 8u + myh];
      ushort a1 = as16[(uint)s1 * 8u + myh];
      ushort a2 = as16[(uint)s2 * 8u + myh];
      ushort a3 = as16[(uint)s3 * 8u + myh];
      __builtin_amdgcn_sched_barrier(0);   // all 8 loads issue before math
      PAIR(a0, h0) PAIR(a1, h1) PAIR(a2, h2) PAIR(a3, h3)
    }
    for (; jj < npair; jj++){
      int s0 = __shfl(sreg, 2 * jj + half);
      uint h0 = h32[(uint)s0 * 32u + li];
      ushort a0 = as16[(uint)s0 * 8u + myh];
      PAIR(a0, h0)
    }
    if (cnt & 1){
      int sl = __shfl(sreg, cnt - 1);
      uint hh = h32[(uint)sl * 32u + li];
      ushort aa = as16[(uint)sl * 8u + myh];
      float e = __half2float(*(__half*)&aa) + ad;
      e = fmaxf(e, NEG * e);
      float p = __expf(fminf(e, 30.f));
      p = half ? 0.f : p;                  // only lower half counts the odd edge
      f32x2 lo = __builtin_amdgcn_cvt_pk_f32_fp8((int)hh, false);
      f32x2 hi = __builtin_amdgcn_cvt_pk_f32_fp8((int)hh, true);
      den += p; acc0 += p * lo[0]; acc1 += p * lo[1];
      acc2 += p * hi[0]; acc3 += p * hi[1];
    }
  }
#undef PAIR

  // fold the two edge-halves
  den  += __shfl_xor(den, 32);
  acc0 += __shfl_xor(acc0, 32);
  acc1 += __shfl_xor(acc1, 32);
  acc2 += __shfl_xor(acc2, 32);
  acc3 += __shfl_xor(acc3, 32);
  float inv = (den > 0.f) ? (1.0f / den) : 0.f;   // den>0 via self-loop
  float v0 = acc0 * inv, v1 = acc1 * inv, v2 = acc2 * inv, v3 = acc3 * inv;
  // head mean: heads live on li bits 2,3,4 -> xor 4, 8, 16
  v0 += __shfl_xor(v0, 4);  v1 += __shfl_xor(v1, 4);  v2 += __shfl_xor(v2, 4);  v3 += __shfl_xor(v3, 4);
  v0 += __shfl_xor(v0, 8);  v1 += __shfl_xor(v1, 8);  v2 += __shfl_xor(v2, 8);  v3 += __shfl_xor(v3, 8);
  v0 += __shfl_xor(v0, 16); v1 += __shfl_xor(v1, 16); v2 += __shfl_xor(v2, 16); v3 += __shfl_xor(v3, 16);
  if (lane < 4){
    int c0 = lane * 4;
    float o0 = v0 * 0.125f + scrub(ldf(bias, c0 + 0, f32));
    float o1 = v1 * 0.125f + scrub(ldf(bias, c0 + 1, f32));
    float o2 = v2 * 0.125f + scrub(ldf(bias, c0 + 2, f32));
    float o3 = v3 * 0.125f + scrub(ldf(bias, c0 + 3, f32));
    o0 = o0 > 0.f ? o0 : (__expf(o0) - 1.0f);
    o1 = o1 > 0.f ? o1 : (__expf(o1) - 1.0f);
    o2 = o2 > 0.f ? o2 : (__expf(o2) - 1.0f);
    o3 = o3 > 0.f ? o3 : (__expf(o3) - 1.0f);
    float4* po = (float4*)(out_n + (size_t)n * 16 + c0);
    *po = make_float4(scrub(o0), scrub(o1), scrub(o2), scrub(o3));
  }
}

// ---- pool: 1 block per graph. Binary-search sorted batch for the segment,
// segmented fp32 reduce of out_n, divide by count, write d_out directly. ----
__global__ __launch_bounds__(256) void k_pool(const float* __restrict__ out_n,
                                              const int* __restrict__ batch,
                                              const int* __restrict__ flags,
                                              float* __restrict__ out){
  int b64 = flags[2];
  int g = blockIdx.x;                  // N_G blocks
  int t = threadIdx.x;
  int c = t & 15, rg = t >> 4;         // 16 channels x 16 row-groups
  int lo = 0, hi = N_NODES;
  while (lo < hi){ int m = (lo + hi) >> 1; if (ldid(batch, m, b64) < g) lo = m + 1; else hi = m; }
  int lo2 = lo, hi2 = N_NODES;
  while (lo2 < hi2){ int m = (lo2 + hi2) >> 1; if (ldid(batch, m, b64) < g + 1) lo2 = m + 1; else hi2 = m; }
  float acc = 0.f;
  for (int r = lo + rg; r < lo2; r += 16)
    acc += out_n[(size_t)r * 16 + c];
  __shared__ float red[16][17];
  red[rg][c] = acc;
  __syncthreads();
  if (t < 16){
    float v = 0.f;
#pragma unroll
    for (int i = 0; i < 16; i++) v += red[i][t];
    float cntf = (float)(lo2 - lo);
    out[g * 16 + t] = scrub(v / fmaxf(cntf, 1.0f));
  }
}

// -----------------------------------------------------------------------------
extern "C" void kernel_launch(void* const* d_in, const int* in_sizes, int n_in,
                              void* d_out, int out_size, void* d_ws, size_t ws_size,
                              hipStream_t stream){
  (void)in_sizes; (void)n_in; (void)out_size; (void)ws_size;
  const void* x     = d_in[0];
  const int*  ei    = (const int*)d_in[1];
  const int*  batch = (const int*)d_in[2];
  const void* gamma = d_in[3];
  const void* beta  = d_in[4];
  const void* W     = d_in[5];
  const void* att_s = d_in[6];
  const void* att_d = d_in[7];
  const void* bias  = d_in[8];

  // ws ~30.7 MB. out_n ALIASES pairBuf (pairBuf dead after k_binC,
  // out_n written by k_msg which launches after).
  char* ws = (char*)d_ws;
  size_t off = 0;
  auto alloc = [&](size_t b){ size_t r = off; off += (b + 255) & ~(size_t)255; return r; };
  int*    flags   = (int*)(ws + alloc(4 * 4));
  float*  stats   = (float*)(ws + alloc(256 * 4));
  float*  Wp      = (float*)(ws + alloc(16384 * 4));
  float*  bp      = (float*)(ws + alloc(128 * 4));
  int*    bcnt    = (int*)(ws + alloc(NB_BUCKETS * 4));
  int*    boff    = (int*)(ws + alloc((NB_BUCKETS + 1) * 4));
  int*    offsets = (int*)(ws + alloc((size_t)(N_NODES + 1) * 4));
  __half* a_src16 = (__half*)(ws + alloc((size_t)N_NODES * 8 * 2));
  __half* a_dst16 = (__half*)(ws + alloc((size_t)N_NODES * 8 * 2));
  size_t  pb_bytes = (size_t)NB_BUCKETS * BCAP * 4;            // 7.43 MB
  size_t  on_bytes = (size_t)N_NODES * 16 * 4;                 // 6.40 MB
  char*   pb_region = ws + alloc(pb_bytes > on_bytes ? pb_bytes : on_bytes);
  uint*   pairBuf = (uint*)pb_region;
  float*  out_n   = (float*)pb_region;   // alias: pairBuf dead before k_msg
  unsigned char* h8 = (unsigned char*)(ws + alloc((size_t)N_NODES * 128));
  int*    csr     = (int*)(ws + alloc((size_t)N_ET * 4));

  hipMemsetAsync(stats, 0, 256 * 4, stream);
  hipMemsetAsync(bcnt,  0, NB_BUCKETS * 4, stream);

  k_detect<<<1, 256, 0, stream>>>((const uint*)x, ei, batch, flags);
  k_bn_stats<<<512, 256, 0, stream>>>(x, flags, stats);
  k_prep<<<1, 128, 0, stream>>>(stats, gamma, beta, W, flags, Wp, bp);
  k_gemm<<<(N_NODES + 127) / 128, 256, 0, stream>>>(x, Wp, bp, att_s, att_d, flags, h8, a_src16, a_dst16);
  k_binAB<<<256, 256, 0, stream>>>(ei, flags, bcnt, pairBuf);
  k_binscan<<<1, 256, 0, stream>>>(bcnt, boff, offsets);
  k_binC<<<NB_BUCKETS, 512, 0, stream>>>(pairBuf, bcnt, boff, offsets, csr);
  k_msg<<<N_NODES / 4, 256, 0, stream>>>(offsets, csr, a_src16, a_dst16, (const uint*)h8, bias, flags, out_n);
  k_pool<<<N_G, 256, 0, stream>>>(out_n, batch, flags, (float*)d_out);
}

// Round 5
// 345.794 us; speedup vs baseline: 3.2616x; 1.0522x over previous
//
#include <hip/hip_runtime.h>
#include <hip/hip_bf16.h>
#include <hip/hip_fp16.h>

// GAT fused pipeline for MI355X.
// R15: k_msg is near its VALU floor (68us, 78% VALUBusy). Attack the
// invisible ~296us: k_gemm was fp32 VALU (3.28 GFLOP, >=40us). Convert to
// bf16 MFMA (mfma_f32_16x16x32_bf16): A = x rows cast bf16 in-reg, B = Wp
// staged once to LDS bf16 with 16B-block XOR swizzle (2-way max conflict),
// C roundtrip through LDS for row-major fp8 pack + fused a_src/a_dst dots.
// Also: k_binscan folded into k_binC (per-block LDS scan of 196 buckets).
// Risk: bf16 GEMM error ~0.4% rel on h (vs fp8's 3% already) and on a-path;
// predict absmax 3e-4 -> 5-7e-4. Revert to fp32 GEMM if FAIL.
// Prediction: k_gemm -> ~15us (MfmaUtil>0), total 364 -> ~310-325us.

#define N_NODES 100000
#define N_EDGE  1600000
#define N_ET    1700000   // edges + self-loops
#define N_G     100
#define HEADS   8
#define OUTC    16
#define EPS     1e-5f
#define NEG     0.2f
#define NB_BUCKETS 196    // ceil(100000 / 512)
#define BCAP    9472      // per-bucket capacity (mean 8704, sigma ~90)
#define EPB     6641      // ceil(N_ET / 256 blocks)

typedef unsigned int uint;
typedef unsigned short ushort;
typedef float f32x2 __attribute__((ext_vector_type(2)));
typedef float f32x4 __attribute__((ext_vector_type(4)));
typedef __bf16 bf16x8 __attribute__((ext_vector_type(8)));

__device__ __forceinline__ float bf2f_lo(uint u){ union{uint i; float f;} c; c.i = u << 16; return c.f; }
__device__ __forceinline__ float bf2f_hi(uint u){ union{uint i; float f;} c; c.i = u & 0xffff0000u; return c.f; }
__device__ __forceinline__ float bf2f(ushort u){ union{uint i; float f;} c; c.i = ((uint)u) << 16; return c.f; }
__device__ __forceinline__ float scrub(float v){ return (v == v) ? v : 0.f; }

// fp32 -> bf16 RNE, NaN -> 0
__device__ __forceinline__ ushort f2bf(float f){
  union{float ff; uint u;} c; c.ff = f;
  uint u = c.u;
  if ((u & 0x7fffffffu) > 0x7f800000u) u = 0;
  return (ushort)((u + 0x7fffu + ((u >> 16) & 1u)) >> 16);
}
__device__ __forceinline__ ushort bfsan(ushort u){
  return ((ushort)(u & 0x7fffu) > (ushort)0x7f80u) ? (ushort)0 : u;
}

__device__ __forceinline__ float ldf(const void* p, int i, int f32){
  return f32 ? ((const float*)p)[i] : bf2f(((const ushort*)p)[i]);
}
__device__ __forceinline__ int ldid(const int* p, int flat, int is64){
  return is64 ? p[2 * flat] : p[flat];
}

// ---------------- dtype detection ----------------
__global__ void k_detect(const uint* __restrict__ x32, const int* __restrict__ ei32,
                         const int* __restrict__ b32, int* __restrict__ flags){
  __shared__ int cnt[3];
  int t = threadIdx.x;
  if (t < 3) cnt[t] = 0;
  __syncthreads();
  { uint w = x32[t]; uint el = (w >> 7) & 0xffu;
    if (el != 0 && (el < 110 || el > 140)) atomicAdd(&cnt[0], 1); }
  if (t < 128){ if (ei32[2 * t + 1] != 0) atomicAdd(&cnt[1], 1); }
  if (t < 128){ if (b32[98001 + 2 * t] != 0) atomicAdd(&cnt[2], 1); }
  __syncthreads();
  if (t == 0){
    flags[0] = cnt[0] > 64;  // 1 = floats are fp32
    flags[1] = cnt[1] < 32;  // 1 = edge_index is int64
    flags[2] = cnt[2] < 32;  // 1 = batch is int64
    flags[3] = 0;
  }
}

// ---------------- BN statistics: column sum / sumsq ----------------
__global__ __launch_bounds__(256) void k_bn_stats(const void* __restrict__ xraw,
                                                  const int* __restrict__ flags,
                                                  float* __restrict__ stats){
  int f32 = flags[0];
  int t = threadIdx.x;
  int c = t & 63;
  int c0 = c * 2;
  float s0 = 0.f, s1 = 0.f, q0 = 0.f, q1 = 0.f;
  if (f32){
    const float2* x2 = (const float2*)xraw;
    for (int r = blockIdx.x * 4 + (t >> 6); r < N_NODES; r += gridDim.x * 4){
      float2 v = x2[r * 64 + c];
      float f0 = scrub(v.x), f1 = scrub(v.y);
      s0 += f0; q0 += f0 * f0;
      s1 += f1; q1 += f1 * f1;
    }
  } else {
    const uint* x2 = (const uint*)xraw;
    for (int r = blockIdx.x * 4 + (t >> 6); r < N_NODES; r += gridDim.x * 4){
      uint v = x2[r * 64 + c];
      float f0 = scrub(bf2f_lo(v)), f1 = scrub(bf2f_hi(v));
      s0 += f0; q0 += f0 * f0;
      s1 += f1; q1 += f1 * f1;
    }
  }
  __shared__ float red[4][256];
  red[0][t] = s0; red[1][t] = q0; red[2][t] = s1; red[3][t] = q1;
  __syncthreads();
  if (t < 64){
    s0 = red[0][t] + red[0][t+64] + red[0][t+128] + red[0][t+192];
    q0 = red[1][t] + red[1][t+64] + red[1][t+128] + red[1][t+192];
    s1 = red[2][t] + red[2][t+64] + red[2][t+128] + red[2][t+192];
    q1 = red[3][t] + red[3][t+64] + red[3][t+128] + red[3][t+192];
    atomicAdd(&stats[c0],       s0);
    atomicAdd(&stats[c0+1],     s1);
    atomicAdd(&stats[128+c0],   q0);
    atomicAdd(&stats[128+c0+1], q1);
  }
}

// ------------- fold BN into GEMM: Wp = scale*W, bp = shift @ W ---------------
__global__ __launch_bounds__(128) void k_prep(const float* __restrict__ stats,
                                              const void* __restrict__ gamma,
                                              const void* __restrict__ beta,
                                              const void* __restrict__ W,
                                              const int* __restrict__ flags,
                                              float* __restrict__ Wp, float* __restrict__ bp){
  int f32 = flags[0];
  __shared__ float scl[128], shf[128];
  int t = threadIdx.x;
  float mean = scrub(stats[t] * (1.0f / N_NODES));
  float var  = stats[128 + t] * (1.0f / N_NODES) - mean * mean;
  if (!(var > 0.f)) var = 0.f;
  float sc = scrub(ldf(gamma, t, f32)) * rsqrtf(var + EPS);
  sc = scrub(sc);
  scl[t] = sc;
  shf[t] = scrub(scrub(ldf(beta, t, f32)) - mean * sc);
  __syncthreads();
  float b = 0.f;
  for (int c = 0; c < 128; c++){
    float w = scrub(ldf(W, c * 128 + t, f32));
    Wp[c * 128 + t] = scl[c] * w;
    b += shf[c] * w;
  }
  bp[t] = scrub(b);
}

// -------- MFMA GEMM h = x @ Wp + bp -> fp8 h8 [N][128B] + attn scalars -------
// 256 thr = 4 waves; block tile 64 rows x 128 cols; K=128 as 4 chunks of 32.
// B staged once: Wp -> bf16 LDS, 16B-block XOR swizzle (blk ^= c&15).
// Epilogue: acc -> LDS fp32 -> row-major fp8 pack + per-head a-dots.
__global__ __launch_bounds__(256) void k_gemm(const void* __restrict__ xraw,
                                              const float* __restrict__ Wp,
                                              const float* __restrict__ bp,
                                              const void* __restrict__ att_src,
                                              const void* __restrict__ att_dst,
                                              const int* __restrict__ flags,
                                              unsigned char* __restrict__ h8,
                                              __half* __restrict__ a_src16,
                                              __half* __restrict__ a_dst16){
  int f32 = flags[0];
  __shared__ __align__(16) char smem[33792];   // BsT 32KB | Cs 64x132 f32
  __shared__ float sSL[128], sDL[128], bpL[128];
  int t = threadIdx.x;
  int wv = t >> 6, l = t & 63;
  int row0 = blockIdx.x * 64;
  if (t < 128){
    sSL[t] = scrub(ldf(att_src, t, f32));
    sDL[t] = scrub(ldf(att_dst, t, f32));
    bpL[t] = bp[t];
  }
  // stage Wp[k][c] -> BsT bf16 at elem c*128 + (k&7) + (((k>>3)^(c&15))<<3)
  ushort* BsT = (ushort*)smem;
#pragma unroll
  for (int i = 0; i < 16; i++){
    int flat = i * 1024 + t * 4;
    int k = flat >> 7, c0 = flat & 127;
    float4 w4 = *(const float4*)(Wp + flat);
    ushort b0 = f2bf(w4.x), b1 = f2bf(w4.y), b2 = f2bf(w4.z), b3 = f2bf(w4.w);
    int kl = k & 7, kb = k >> 3;
    BsT[(c0+0) * 128 + kl + ((kb ^ ((c0+0) & 15)) << 3)] = b0;
    BsT[(c0+1) * 128 + kl + ((kb ^ ((c0+1) & 15)) << 3)] = b1;
    BsT[(c0+2) * 128 + kl + ((kb ^ ((c0+2) & 15)) << 3)] = b2;
    BsT[(c0+3) * 128 + kl + ((kb ^ ((c0+3) & 15)) << 3)] = b3;
  }
  __syncthreads();

  f32x4 acc[8];
#pragma unroll
  for (int ct = 0; ct < 8; ct++) acc[ct] = (f32x4){0.f, 0.f, 0.f, 0.f};
  int arow = row0 + wv * 16 + (l & 15);
  int cr = min(arow, N_NODES - 1);
  int kg = (l >> 4) * 8;
  union AB { uint4 q; bf16x8 v; ushort u[8]; };
#pragma unroll
  for (int kc = 0; kc < 4; kc++){
    AB a;
    if (f32){
      const float* xr = (const float*)xraw + (size_t)cr * 128 + kc * 32 + kg;
      float4 p0 = *(const float4*)xr;
      float4 p1 = *(const float4*)(xr + 4);
      a.u[0] = f2bf(p0.x); a.u[1] = f2bf(p0.y); a.u[2] = f2bf(p0.z); a.u[3] = f2bf(p0.w);
      a.u[4] = f2bf(p1.x); a.u[5] = f2bf(p1.y); a.u[6] = f2bf(p1.z); a.u[7] = f2bf(p1.w);
    } else {
      const ushort* xr = (const ushort*)xraw + (size_t)cr * 128 + kc * 32 + kg;
      a.q = *(const uint4*)xr;
#pragma unroll
      for (int j = 0; j < 8; j++) a.u[j] = bfsan(a.u[j]);
    }
#pragma unroll
    for (int ct = 0; ct < 8; ct++){
      int c = ct * 16 + (l & 15);
      int kb = kc * 4 + (l >> 4);
      AB bfr;
      bfr.q = *(const uint4*)(BsT + c * 128 + ((kb ^ (c & 15)) << 3));
      acc[ct] = __builtin_amdgcn_mfma_f32_16x16x32_bf16(a.v, bfr.v, acc[ct], 0, 0, 0);
    }
  }
  __syncthreads();
  // C -> LDS fp32 [64][132]
  float* Cs = (float*)smem;
#pragma unroll
  for (int ct = 0; ct < 8; ct++){
#pragma unroll
    for (int ri = 0; ri < 4; ri++)
      Cs[(wv * 16 + (l >> 4) * 4 + ri) * 132 + ct * 16 + (l & 15)] = acc[ct][ri];
  }
  __syncthreads();
  // pack fp8 + per-head attention dots. thread t: row t>>2, 32 cols (2 heads).
  int row = t >> 2, cg = (t & 3) * 32;
  int r = row0 + row;
  if (r < N_NODES){
    float o[32];
#pragma unroll
    for (int i = 0; i < 8; i++){
      float4 v = *(const float4*)(Cs + row * 132 + cg + i * 4);
      o[i*4+0] = v.x; o[i*4+1] = v.y; o[i*4+2] = v.z; o[i*4+3] = v.w;
    }
#pragma unroll
    for (int j = 0; j < 32; j++){
      float v = scrub(o[j] + bpL[cg + j]);
      o[j] = fminf(fmaxf(v, -448.f), 448.f);   // e4m3 sat guard
    }
    uint w[8];
#pragma unroll
    for (int i = 0; i < 8; i++){
      uint ww = __builtin_amdgcn_cvt_pk_fp8_f32(o[i*4+0], o[i*4+1], 0, false);
      w[i] = __builtin_amdgcn_cvt_pk_fp8_f32(o[i*4+2], o[i*4+3], (int)ww, true);
    }
    unsigned char* po = h8 + (size_t)r * 128 + cg;
    *(uint4*)po        = make_uint4(w[0], w[1], w[2], w[3]);
    *(uint4*)(po + 16) = make_uint4(w[4], w[5], w[6], w[7]);
    float s0 = 0.f, s1 = 0.f, d0 = 0.f, d1 = 0.f;
#pragma unroll
    for (int j = 0; j < 16; j++){
      s0 += o[j]      * sSL[cg + j];      d0 += o[j]      * sDL[cg + j];
      s1 += o[16 + j] * sSL[cg + 16 + j]; d1 += o[16 + j] * sDL[cg + 16 + j];
    }
    int hA = (t & 3) * 2;
    *(__half2*)(a_src16 + (size_t)r * 8 + hA) = __floats2half2_rn(scrub(s0), scrub(s1));
    *(__half2*)(a_dst16 + (size_t)r * 8 + hA) = __floats2half2_rn(scrub(d0), scrub(d1));
  }
}

// --------------------- CSR build: 2-level bucket scatter ---------------------
// merged pass A+B: LDS histogram -> one global cursor grab per bucket ->
// write packed (src<<9 | dst&511) into bucket-run region b*BCAP.
__global__ __launch_bounds__(256) void k_binAB(const int* __restrict__ ei,
                                               const int* __restrict__ flags,
                                               int* __restrict__ bcnt,
                                               uint* __restrict__ pairBuf){
  int is64 = flags[1];
  __shared__ int hist[NB_BUCKETS];
  __shared__ int base[NB_BUCKETS];
  int t = threadIdx.x;
  for (int i = t; i < NB_BUCKETS; i += 256) hist[i] = 0;
  __syncthreads();
  int e0 = blockIdx.x * EPB, e1 = min(e0 + EPB, N_ET);
  for (int e = e0 + t; e < e1; e += 256){
    int d = (e < N_EDGE) ? ldid(ei, N_EDGE + e, is64) : (e - N_EDGE);
    uint b = (uint)d >> 9; if (b >= NB_BUCKETS) b = NB_BUCKETS - 1;
    atomicAdd(&hist[b], 1);
  }
  __syncthreads();
  for (int i = t; i < NB_BUCKETS; i += 256){
    int c = hist[i];
    base[i] = c ? atomicAdd(&bcnt[i], c) : 0;
    hist[i] = 0;               // reuse as local cursor
  }
  __syncthreads();
  for (int e = e0 + t; e < e1; e += 256){
    int s, d;
    if (e < N_EDGE){ s = ldid(ei, e, is64); d = ldid(ei, N_EDGE + e, is64); }
    else { s = d = e - N_EDGE; }
    uint b = (uint)d >> 9; if (b >= NB_BUCKETS) b = NB_BUCKETS - 1;
    int pos = base[b] + atomicAdd(&hist[b], 1);
    if ((uint)pos < BCAP) pairBuf[(size_t)b * BCAP + pos] = ((uint)s << 9) | ((uint)d & 511u);
  }
}

// pass C (scan folded in): each block scans the 196 bucket counts in LDS,
// then LDS degree count + scan -> offsets (sequential) + csr scatter confined
// to the bucket's ~35KB region (1 CU).
__global__ __launch_bounds__(512) void k_binC(const uint* __restrict__ pairBuf,
                                              const int* __restrict__ bcnt,
                                              int* __restrict__ offsets,
                                              int* __restrict__ csr){
  int b = blockIdx.x, t = threadIdx.x;
  __shared__ int sscan[256];
  __shared__ int degL[512];
  __shared__ int offL[512];
  __shared__ int curL[512];
  if (t < 256) sscan[t] = (t < NB_BUCKETS) ? min(bcnt[t], BCAP) : 0;
  degL[t] = 0;
  __syncthreads();
  for (int off = 1; off < 256; off <<= 1){
    int add = (t < 256 && t >= off) ? sscan[t - off] : 0;
    __syncthreads();
    if (t < 256) sscan[t] += add;
    __syncthreads();
  }
  int gbase = (b == 0) ? 0 : sscan[b - 1];
  if (b == NB_BUCKETS - 1 && t == 0) offsets[N_NODES] = sscan[NB_BUCKETS - 1];
  int cnt = min(bcnt[b], BCAP);
  const uint* run = pairBuf + (size_t)b * BCAP;
  for (int i = t; i < cnt; i += 512)
    atomicAdd(&degL[run[i] & 511u], 1);
  __syncthreads();
  int v = degL[t];
  offL[t] = v;
  __syncthreads();
  for (int off = 1; off < 512; off <<= 1){
    int add = (t >= off) ? offL[t - off] : 0;
    __syncthreads();
    offL[t] += add;
    __syncthreads();
  }
  int excl = offL[t] - v;
  int node = (b << 9) + t;
  if (node < N_NODES) offsets[node] = gbase + excl;
  offL[t] = excl;              // own-entry rewrite, no cross-read hazard
  curL[t] = 0;
  __syncthreads();
  for (int i = t; i < cnt; i += 512){
    uint e = run[i];
    int dl = e & 511u;
    int s  = e >> 9;
    int pos = atomicAdd(&curL[dl], 1);
    csr[gbase + offL[dl] + pos] = s;
  }
}

// ------ fused: inline softmax + fp8 gather + head-mean + ELU -> out_n.
// One wave per node; lane owns 4 channels (li=lane&31 -> ch li*4..+3,
// head myh=li>>2); wave halves process 2 edges simultaneously.
__global__ __launch_bounds__(256) void k_msg(const int* __restrict__ offsets, const int* __restrict__ csr,
                                             const __half* __restrict__ a_src16, const __half* __restrict__ a_dst16,
                                             const uint* __restrict__ h32, const void* __restrict__ bias,
                                             const int* __restrict__ flags,
                                             float* __restrict__ out_n){
  int f32 = flags[0];
  int t = threadIdx.x;
  int wv = t >> 6, lane = t & 63;
  int half = lane >> 5, li = lane & 31;
  int myh = li >> 2;
  int n = blockIdx.x * 4 + wv;        // grid = N/4 exactly
  int start = offsets[n], end = offsets[n + 1];
  float ad = __half2float(a_dst16[(size_t)n * 8 + myh]);
  const ushort* as16 = (const ushort*)a_src16;
  float acc0 = 0.f, acc1 = 0.f, acc2 = 0.f, acc3 = 0.f, den = 0.f;

#define PAIR(AA, HH)                                                  \
  { float e = __half2float(*(__half*)&(AA)) + ad;                     \
    e = fmaxf(e, NEG * e);                                            \
    float p = __expf(fminf(e, 30.f));                                 \
    f32x2 lo = __builtin_amdgcn_cvt_pk_f32_fp8((int)(HH), false);     \
    f32x2 hi = __builtin_amdgcn_cvt_pk_f32_fp8((int)(HH), true);      \
    den += p; acc0 += p * lo[0]; acc1 += p * lo[1];                   \
    acc2 += p * hi[0]; acc3 += p * hi[1]; }

  for (int base = start; base < end; base += 64){
    int cnt = min(64, end - base);
    int sreg = csr[min(base + lane, N_ET - 1)];
    int npair = cnt >> 1;
    int jj = 0;
    for (; jj + 4 <= npair; jj += 4){
      int i0 = 2 * jj + half;
      int s0 = __shfl(sreg, i0);
      int s1 = __shfl(sreg, i0 + 2);
      int s2 = __shfl(sreg, i0 + 4);
      int s3 = __shfl(sreg, i0 + 6);
      uint h0 = h32[(uint)s0 * 32u + li];
      uint h1 = h32[(uint)s1 * 32u + li];
      uint h2 = h32[(uint)s2 * 32u + li];
      uint h3 = h32[(uint)s3 * 32u + li];
      ushort a0 = as16[(uint)s0 * 8u + myh];
      ushort a1 = as16[(uint)s1 * 8u + myh];
      ushort a2 = as16[(uint)s2 * 8u + myh];
      ushort a3 = as16[(uint)s3 * 8u + myh];
      __builtin_amdgcn_sched_barrier(0);   // all 8 loads issue before math
      PAIR(a0, h0) PAIR(a1, h1) PAIR(a2, h2) PAIR(a3, h3)
    }
    for (; jj < npair; jj++){
      int s0 = __shfl(sreg, 2 * jj + half);
      uint h0 = h32[(uint)s0 * 32u + li];
      ushort a0 = as16[(uint)s0 * 8u + myh];
      PAIR(a0, h0)
    }
    if (cnt & 1){
      int sl = __shfl(sreg, cnt - 1);
      uint hh = h32[(uint)sl * 32u + li];
      ushort aa = as16[(uint)sl * 8u + myh];
      float e = __half2float(*(__half*)&aa) + ad;
      e = fmaxf(e, NEG * e);
      float p = __expf(fminf(e, 30.f));
      p = half ? 0.f : p;                  // only lower half counts the odd edge
      f32x2 lo = __builtin_amdgcn_cvt_pk_f32_fp8((int)hh, false);
      f32x2 hi = __builtin_amdgcn_cvt_pk_f32_fp8((int)hh, true);
      den += p; acc0 += p * lo[0]; acc1 += p * lo[1];
      acc2 += p * hi[0]; acc3 += p * hi[1];
    }
  }
#undef PAIR

  // fold the two edge-halves
  den  += __shfl_xor(den, 32);
  acc0 += __shfl_xor(acc0, 32);
  acc1 += __shfl_xor(acc1, 32);
  acc2 += __shfl_xor(acc2, 32);
  acc3 += __shfl_xor(acc3, 32);
  float inv = (den > 0.f) ? (1.0f / den) : 0.f;   // den>0 via self-loop
  float v0 = acc0 * inv, v1 = acc1 * inv, v2 = acc2 * inv, v3 = acc3 * inv;
  // head mean: heads live on li bits 2,3,4 -> xor 4, 8, 16
  v0 += __shfl_xor(v0, 4);  v1 += __shfl_xor(v1, 4);  v2 += __shfl_xor(v2, 4);  v3 += __shfl_xor(v3, 4);
  v0 += __shfl_xor(v0, 8);  v1 += __shfl_xor(v1, 8);  v2 += __shfl_xor(v2, 8);  v3 += __shfl_xor(v3, 8);
  v0 += __shfl_xor(v0, 16); v1 += __shfl_xor(v1, 16); v2 += __shfl_xor(v2, 16); v3 += __shfl_xor(v3, 16);
  if (lane < 4){
    int c0 = lane * 4;
    float o0 = v0 * 0.125f + scrub(ldf(bias, c0 + 0, f32));
    float o1 = v1 * 0.125f + scrub(ldf(bias, c0 + 1, f32));
    float o2 = v2 * 0.125f + scrub(ldf(bias, c0 + 2, f32));
    float o3 = v3 * 0.125f + scrub(ldf(bias, c0 + 3, f32));
    o0 = o0 > 0.f ? o0 : (__expf(o0) - 1.0f);
    o1 = o1 > 0.f ? o1 : (__expf(o1) - 1.0f);
    o2 = o2 > 0.f ? o2 : (__expf(o2) - 1.0f);
    o3 = o3 > 0.f ? o3 : (__expf(o3) - 1.0f);
    float4* po = (float4*)(out_n + (size_t)n * 16 + c0);
    *po = make_float4(scrub(o0), scrub(o1), scrub(o2), scrub(o3));
  }
}

// ---- pool: 1 block per graph. Binary-search sorted batch for the segment,
// segmented fp32 reduce of out_n, divide by count, write d_out directly. ----
__global__ __launch_bounds__(256) void k_pool(const float* __restrict__ out_n,
                                              const int* __restrict__ batch,
                                              const int* __restrict__ flags,
                                              float* __restrict__ out){
  int b64 = flags[2];
  int g = blockIdx.x;                  // N_G blocks
  int t = threadIdx.x;
  int c = t & 15, rg = t >> 4;         // 16 channels x 16 row-groups
  int lo = 0, hi = N_NODES;
  while (lo < hi){ int m = (lo + hi) >> 1; if (ldid(batch, m, b64) < g) lo = m + 1; else hi = m; }
  int lo2 = lo, hi2 = N_NODES;
  while (lo2 < hi2){ int m = (lo2 + hi2) >> 1; if (ldid(batch, m, b64) < g + 1) lo2 = m + 1; else hi2 = m; }
  float acc = 0.f;
  for (int r = lo + rg; r < lo2; r += 16)
    acc += out_n[(size_t)r * 16 + c];
  __shared__ float red[16][17];
  red[rg][c] = acc;
  __syncthreads();
  if (t < 16){
    float v = 0.f;
#pragma unroll
    for (int i = 0; i < 16; i++) v += red[i][t];
    float cntf = (float)(lo2 - lo);
    out[g * 16 + t] = scrub(v / fmaxf(cntf, 1.0f));
  }
}

// -----------------------------------------------------------------------------
extern "C" void kernel_launch(void* const* d_in, const int* in_sizes, int n_in,
                              void* d_out, int out_size, void* d_ws, size_t ws_size,
                              hipStream_t stream){
  (void)in_sizes; (void)n_in; (void)out_size; (void)ws_size;
  const void* x     = d_in[0];
  const int*  ei    = (const int*)d_in[1];
  const int*  batch = (const int*)d_in[2];
  const void* gamma = d_in[3];
  const void* beta  = d_in[4];
  const void* W     = d_in[5];
  const void* att_s = d_in[6];
  const void* att_d = d_in[7];
  const void* bias  = d_in[8];

  // ws ~30.7 MB. out_n ALIASES pairBuf (pairBuf dead after k_binC).
  char* ws = (char*)d_ws;
  size_t off = 0;
  auto alloc = [&](size_t b){ size_t r = off; off += (b + 255) & ~(size_t)255; return r; };
  int*    flags   = (int*)(ws + alloc(4 * 4));
  float*  stats   = (float*)(ws + alloc(256 * 4));
  float*  Wp      = (float*)(ws + alloc(16384 * 4));
  float*  bp      = (float*)(ws + alloc(128 * 4));
  int*    bcnt    = (int*)(ws + alloc(NB_BUCKETS * 4));
  int*    offsets = (int*)(ws + alloc((size_t)(N_NODES + 1) * 4));
  __half* a_src16 = (__half*)(ws + alloc((size_t)N_NODES * 8 * 2));
  __half* a_dst16 = (__half*)(ws + alloc((size_t)N_NODES * 8 * 2));
  size_t  pb_bytes = (size_t)NB_BUCKETS * BCAP * 4;            // 7.43 MB
  size_t  on_bytes = (size_t)N_NODES * 16 * 4;                 // 6.40 MB
  char*   pb_region = ws + alloc(pb_bytes > on_bytes ? pb_bytes : on_bytes);
  uint*   pairBuf = (uint*)pb_region;
  float*  out_n   = (float*)pb_region;   // alias: pairBuf dead before k_msg
  unsigned char* h8 = (unsigned char*)(ws + alloc((size_t)N_NODES * 128));
  int*    csr     = (int*)(ws + alloc((size_t)N_ET * 4));

  hipMemsetAsync(stats, 0, 256 * 4, stream);
  hipMemsetAsync(bcnt,  0, NB_BUCKETS * 4, stream);

  k_detect<<<1, 256, 0, stream>>>((const uint*)x, ei, batch, flags);
  k_bn_stats<<<512, 256, 0, stream>>>(x, flags, stats);
  k_prep<<<1, 128, 0, stream>>>(stats, gamma, beta, W, flags, Wp, bp);
  k_gemm<<<(N_NODES + 63) / 64, 256, 0, stream>>>(x, Wp, bp, att_s, att_d, flags, h8, a_src16, a_dst16);
  k_binAB<<<256, 256, 0, stream>>>(ei, flags, bcnt, pairBuf);
  k_binC<<<NB_BUCKETS, 512, 0, stream>>>(pairBuf, bcnt, offsets, csr);
  k_msg<<<N_NODES / 4, 256, 0, stream>>>(offsets, csr, a_src16, a_dst16, (const uint*)h8, bias, flags, out_n);
  k_pool<<<N_G, 256, 0, stream>>>(out_n, batch, flags, (float*)d_out);
}